// Round 8
// baseline (563.175 us; speedup 1.0000x reference)
//
#include <hip/hip_runtime.h>
#include <cstdint>

typedef __attribute__((ext_vector_type(8))) __bf16 bf16x8;
typedef __attribute__((ext_vector_type(4))) __bf16 bf16x4;
typedef __attribute__((ext_vector_type(4))) float f32x4;
typedef unsigned long long u64;

__device__ __forceinline__ void gld_lds16(const void* g, void* l) {
  __builtin_amdgcn_global_load_lds(
      (const __attribute__((address_space(1))) void*)g,
      (__attribute__((address_space(3))) void*)l, 16, 0, 0);
}

__device__ __forceinline__ float block_sum(float v, float* scr) {
#pragma unroll
  for (int off = 32; off > 0; off >>= 1) v += __shfl_down(v, off, 64);
  const int w = threadIdx.x >> 6;
  __syncthreads();
  if ((threadIdx.x & 63) == 0) scr[w] = v;
  __syncthreads();
  float s = 0.f;
  const int nw = blockDim.x >> 6;
  for (int i = 0; i < nw; ++i) s += scr[i];
  return s;
}

// fast gelu: A&S 7.1.26 erf (|err|<1.5e-7) + hw exp
__device__ __forceinline__ float gelu_fast(float x) {
  const float ax = fabsf(x) * 0.70710678118654752f;
  const float t = 1.f / (1.f + 0.3275911f * ax);
  const float e = __expf(-ax * ax);
  float poly = 1.061405429f;
  poly = poly * t - 1.453152027f;
  poly = poly * t + 1.421413741f;
  poly = poly * t - 0.284496736f;
  poly = poly * t + 0.254829592f;
  const float erfax = 1.f - poly * t * e;
  const float er = copysignf(erfax, x);
  return 0.5f * x * (1.f + er);
}

// ---------------- casts ----------------
__global__ __launch_bounds__(256) void k_cast_bf16(const float* __restrict__ in,
                                                   __bf16* __restrict__ out) {
  const long i = ((long)blockIdx.x * 256 + threadIdx.x) * 4;
  f32x4 v = *(const f32x4*)(in + i);
  bf16x4 o = {(__bf16)v[0], (__bf16)v[1], (__bf16)v[2], (__bf16)v[3]};
  *(bf16x4*)(out + i) = o;
}

__global__ __launch_bounds__(256) void k_cast_pad(const float* __restrict__ in,
                                                  __bf16* __restrict__ out,
                                                  int rows_real, int cols) {
  const long i = ((long)blockIdx.x * 256 + threadIdx.x) * 4;
  const int row = (int)(i / cols);
  const int col = (int)(i % cols);
  bf16x4 o;
  if (row < rows_real) {
    f32x4 v = *(const f32x4*)(in + (long)row * cols + col);
    o = (bf16x4){(__bf16)v[0], (__bf16)v[1], (__bf16)v[2], (__bf16)v[3]};
  } else {
    o = (bf16x4){(__bf16)0.f, (__bf16)0.f, (__bf16)0.f, (__bf16)0.f};
  }
  *(bf16x4*)(out + i) = o;
}

// ---------------- transpose 1024x1024 f32 ----------------
__global__ __launch_bounds__(256) void k_transpose1k(const float* __restrict__ in,
                                                     float* __restrict__ out) {
  __shared__ float t[32][33];
  const int tx = threadIdx.x & 31;
  const int ty = threadIdx.x >> 5;
  const int r0 = blockIdx.y * 32, c0 = blockIdx.x * 32;
#pragma unroll
  for (int k = 0; k < 4; ++k)
    t[ty + 8 * k][tx] = in[(long)(r0 + ty + 8 * k) * 1024 + c0 + tx];
  __syncthreads();
#pragma unroll
  for (int k = 0; k < 4; ++k)
    out[(long)(c0 + ty + 8 * k) * 1024 + r0 + tx] = t[tx][ty + 8 * k];
}

// ============ 256x256 8-wave BK=64 phase-interleaved GEMM (bf16 out) ============
// C = A @ B^T + bias. M%256==0, N%256==0, K%64==0, grid (N/256, M/256), 512 thr.
// Deep prefetch: ALL staging for tile t+1 issued at top of tile t (distance =
// 4 phases ~ full HBM latency), per-wave vmcnt(8) keeps them in flight (T3+T4).
// XOR bank-swizzle both sides (T2), setprio (T5), bijective XCD swizzle (T1).
__global__ __launch_bounds__(512, 1) void k_gemm256_bt(
    const __bf16* __restrict__ A, const __bf16* __restrict__ B,
    const float* __restrict__ bias, __bf16* __restrict__ C,
    int M, int N, int K) {
  __shared__ __align__(16) __bf16 lds[2][2][256 * 64];  // [slot][mat][row*64+k]
  const int tid = threadIdx.x;
  const int lane = tid & 63;
  const int wid = tid >> 6;
  const int wr = wid >> 2;   // 0..1 : 128-row group
  const int wc = wid & 3;    // 0..3 : 64-col group
  const int gx = gridDim.x, gy = gridDim.y;
  const int nwg = gx * gy;
  const int lin = blockIdx.y * gx + blockIdx.x;
  const int cpx = nwg >> 3;  // nwg % 8 == 0 by construction
  const int wsw = (lin & 7) * cpx + (lin >> 3);
  const int bx = wsw / gy, by = wsw % gy;
  const int m0 = by * 256, n0 = bx * 256;
  const int fr = lane & 15;  // fragment row
  const int fx = lane >> 4;  // 0..3 : k-subgroup
  const int px = lane & 7;   // read-side swizzle key (== row&7 for all frags)

  const __bf16* Abase = A + (long)m0 * K;
  const __bf16* Bbase = B + (long)n0 * K;

  // stage one quarter-tile (128 rows x 64 k) of tile kt into slot: 2 gload_lds.
  // LDS dest linear; global source pre-swizzled with the involution blk^=row&7.
  auto stage_q = [&](int slot, int kt, int mat, int half) {
    const __bf16* src = (mat ? Bbase : Abase) + kt * 64;
#pragma unroll
    for (int q = 0; q < 2; ++q) {
      const int idx = q * 512 + tid;   // [0,1024)
      const int r = idx >> 3;          // 0..127
      const int pblk = idx & 7;        // 16B block within 128B row
      const int row = half * 128 + r;
      const int lblk = pblk ^ (r & 7); // involution
      gld_lds16(src + (long)row * K + lblk * 8,
                (char*)&lds[slot][mat][row * 64 + pblk * 8]);
    }
  };
  // read a bf16x8 fragment (row, k-slice ks) with swizzled block index
  auto frag = [&](int slot, int mat, int row, int ks) -> bf16x8 {
    return *(const bf16x8*)&lds[slot][mat][row * 64 + ((((ks << 2) + fx) ^ px) << 3)];
  };

  f32x4 acc[8][4] = {};
  const int nt = K >> 6;
  // prologue: full tile 0 -> slot 0 (8 loads/thread outstanding)
#pragma unroll
  for (int qp = 0; qp < 4; ++qp) stage_q(0, 0, qp >> 1, qp & 1);

  const int arow = wr * 128 + fr;
  const int brow = wc * 64 + fr;

  for (int t = 0; t < nt; ++t) {
    const int sc = t & 1, sn = sc ^ 1;
    const bool pf = (t + 1 < nt);
    // ---- deep prefetch: issue the ENTIRE next tile now (8 loads/thread),
    //      then wait for current tile's 8 (keep the 8 newest in flight) ----
    if (pf) {
#pragma unroll
      for (int qp = 0; qp < 4; ++qp) stage_q(sn, t + 1, qp >> 1, qp & 1);
      asm volatile("s_waitcnt vmcnt(8)" ::: "memory");
    } else {
      asm volatile("s_waitcnt vmcnt(0)" ::: "memory");
    }
    __builtin_amdgcn_sched_barrier(0);
    __builtin_amdgcn_s_barrier();  // publish all waves' staging of slot sc
    // B fragments for both k-slices (persist across phases)
    bf16x8 b0[4], b1[4];
#pragma unroll
    for (int j = 0; j < 4; ++j) {
      b0[j] = frag(sc, 1, brow + j * 16, 0);
      b1[j] = frag(sc, 1, brow + j * 16, 1);
    }
#define DO_PHASE(P)                                                            \
  {                                                                            \
    bf16x8 a00 = frag(sc, 0, arow + (2 * (P)) * 16, 0);                        \
    bf16x8 a01 = frag(sc, 0, arow + (2 * (P)) * 16, 1);                        \
    bf16x8 a10 = frag(sc, 0, arow + (2 * (P) + 1) * 16, 0);                    \
    bf16x8 a11 = frag(sc, 0, arow + (2 * (P) + 1) * 16, 1);                    \
    __builtin_amdgcn_s_barrier();                                              \
    __builtin_amdgcn_s_setprio(1);                                             \
    _Pragma("unroll") for (int j = 0; j < 4; ++j) {                            \
      acc[2 * (P)][j] = __builtin_amdgcn_mfma_f32_16x16x32_bf16(               \
          a00, b0[j], acc[2 * (P)][j], 0, 0, 0);                               \
      acc[2 * (P)][j] = __builtin_amdgcn_mfma_f32_16x16x32_bf16(               \
          a01, b1[j], acc[2 * (P)][j], 0, 0, 0);                               \
      acc[2 * (P) + 1][j] = __builtin_amdgcn_mfma_f32_16x16x32_bf16(           \
          a10, b0[j], acc[2 * (P) + 1][j], 0, 0, 0);                           \
      acc[2 * (P) + 1][j] = __builtin_amdgcn_mfma_f32_16x16x32_bf16(           \
          a11, b1[j], acc[2 * (P) + 1][j], 0, 0, 0);                           \
    }                                                                          \
    __builtin_amdgcn_s_setprio(0);                                             \
    __builtin_amdgcn_s_barrier();                                              \
  }
    DO_PHASE(0)
    DO_PHASE(1)
    DO_PHASE(2)
    DO_PHASE(3)
#undef DO_PHASE
  }

  const int crow0 = m0 + wr * 128 + fx * 4;
  const int ccol0 = n0 + wc * 64 + fr;
#pragma unroll
  for (int j = 0; j < 4; ++j) {
    const int col = ccol0 + j * 16;
    const float bv = bias[col];
#pragma unroll
    for (int im = 0; im < 8; ++im)
#pragma unroll
      for (int r = 0; r < 4; ++r)
        C[(long)(crow0 + im * 16 + r) * N + col] = (__bf16)(acc[im][j][r] + bv);
  }
}

// ---------------- GEMM: C = A @ B^T + bias (128-col tiles) ----------------
// EPI: 0 f32, 1 bf16, 4 fused self-mod update
template <int EPI, int BM>
__global__ __launch_bounds__(256) void k_gemm_bt(
    const __bf16* __restrict__ A, const __bf16* __restrict__ B,
    const float* __restrict__ bias, void* __restrict__ Cout,
    int M, int N, int K, int Nreal,
    float* __restrict__ supR, float* __restrict__ supI) {
  constexpr int MR = BM / 32;
  __shared__ __align__(16) __bf16 As[2][BM * 32];
  __shared__ __align__(16) __bf16 Bs[2][128 * 32];
  const int tid = threadIdx.x;
  const int lane = tid & 63;
  const int wid = tid >> 6;
  const int wr = wid >> 1, wc = wid & 1;

  const int gx = gridDim.x, gy = gridDim.y;
  const int nwg = gx * gy;
  int bx, by;
  if ((nwg & 7) == 0) {
    const int lin = blockIdx.y * gx + blockIdx.x;
    const int cpx = nwg >> 3;
    const int w = (lin & 7) * cpx + (lin >> 3);
    bx = w / gy;
    by = w % gy;
  } else {
    bx = blockIdx.x;
    by = blockIdx.y;
  }
  const int m0 = by * BM;
  const int n0 = bx * 128;
  const int frow = lane & 15;
  const int fk = (lane >> 4) * 8;
  f32x4 acc[MR][4] = {};

  auto stage = [&](int buf, int k0) {
    const __bf16* Ab = A + (long)m0 * K + k0;
    const __bf16* Bb = B + (long)n0 * K + k0;
#pragma unroll
    for (int q = 0; q < BM / 64; ++q) {
      const int idx = q * 256 + tid;
      const int row = idx >> 2;
      const int col = (idx & 3) * 8;
      gld_lds16(Ab + (long)row * K + col, (char*)(&As[buf][0]) + idx * 16);
    }
#pragma unroll
    for (int q = 0; q < 2; ++q) {
      const int idx = q * 256 + tid;
      const int row = idx >> 2;
      const int col = (idx & 3) * 8;
      gld_lds16(Bb + (long)row * K + col, (char*)(&Bs[buf][0]) + idx * 16);
    }
  };

  const int nt = K >> 5;
  int cur = 0;
  stage(0, 0);
  __syncthreads();
  for (int t = 0; t < nt; ++t) {
    if (t + 1 < nt) stage(cur ^ 1, (t + 1) << 5);
    bf16x8 af[MR], bfr[4];
#pragma unroll
    for (int i = 0; i < MR; ++i)
      af[i] = *(const bf16x8*)(&As[cur][0] + (wr * (BM / 2) + i * 16 + frow) * 32 + fk);
#pragma unroll
    for (int i = 0; i < 4; ++i)
      bfr[i] = *(const bf16x8*)(&Bs[cur][0] + (wc * 64 + i * 16 + frow) * 32 + fk);
#pragma unroll
    for (int im = 0; im < MR; ++im)
#pragma unroll
      for (int in = 0; in < 4; ++in)
        acc[im][in] = __builtin_amdgcn_mfma_f32_16x16x32_bf16(af[im], bfr[in],
                                                              acc[im][in], 0, 0, 0);
    __syncthreads();
    cur ^= 1;
  }

  const int crow0 = m0 + wr * (BM / 2) + (lane >> 4) * 4;
  const int ccol0 = n0 + wc * 64 + (lane & 15);
#pragma unroll
  for (int in = 0; in < 4; ++in) {
    const int col = ccol0 + in * 16;
    if (col >= Nreal) continue;
    const float bv = bias[col];
#pragma unroll
    for (int im = 0; im < MR; ++im) {
#pragma unroll
      for (int r = 0; r < 4; ++r) {
        const long row = crow0 + im * 16 + r;
        const float v = acc[im][in][r] + bv;
        if (EPI == 0) {
          ((float*)Cout)[row * Nreal + col] = v;
        } else if (EPI == 1) {
          ((__bf16*)Cout)[row * Nreal + col] = (__bf16)v;
        } else {
          const float gmul = 1.f / (1.f + __expf(-v)) + 0.1f;
          const long ix = row * Nreal + col;
          supR[ix] *= gmul;
          supI[ix] *= gmul;
        }
      }
    }
  }
}

// ---------------- LN (over 1024) + gelu -> bf16 ----------------
__global__ __launch_bounds__(256) void k_ln_gelu(const float* __restrict__ y,
                                                 const float* __restrict__ g,
                                                 const float* __restrict__ b,
                                                 __bf16* __restrict__ h) {
  __shared__ float scr[8];
  const int tid = threadIdx.x;
  const long row = blockIdx.x;
  const float* yr = y + row * 1024;
  f32x4 v = *(const f32x4*)(yr + tid * 4);
  float ls = v[0] + v[1] + v[2] + v[3];
  const float mu = block_sum(ls, scr) * (1.f / 1024.f);
  float lss = 0.f;
#pragma unroll
  for (int j = 0; j < 4; ++j) {
    const float d = v[j] - mu;
    lss += d * d;
  }
  const float var = block_sum(lss, scr) * (1.f / 1024.f);
  const float rstd = rsqrtf(var + 1e-5f);
  bf16x4 o;
#pragma unroll
  for (int j = 0; j < 4; ++j) {
    const int c = tid * 4 + j;
    const float t = (v[j] - mu) * rstd * g[c] + b[c];
    o[j] = (__bf16)gelu_fast(t);
  }
  *(bf16x4*)(h + row * 1024 + tid * 4) = o;
}

// ---------------- stage C ----------------
__global__ __launch_bounds__(256) void k_stage_c(
    const __bf16* __restrict__ outb, const float* __restrict__ ln_g,
    const float* __restrict__ ln_b, const float* __restrict__ phases,
    const float* __restrict__ temp, float* __restrict__ supr,
    float* __restrict__ supi, int b0) {
  __shared__ float wrs[3][1024];
  __shared__ float wis[3][1024];
  __shared__ float gbuf[2048];
  __shared__ float scr[8];
  const int tid = threadIdx.x;
  const long b = blockIdx.x;

#pragma unroll 1
  for (int s = 0; s < 3; ++s) {
    const __bf16* src = outb + b * 6144 + s * 2048;
    bf16x8 v8 = *(const bf16x8*)(src + tid * 8);
    float x[8];
#pragma unroll
    for (int j = 0; j < 8; ++j) x[j] = (float)v8[j];
    float ls = 0.f;
#pragma unroll
    for (int j = 0; j < 8; ++j) ls += x[j];
    const float mu = block_sum(ls, scr) * (1.f / 2048.f);
    float lss = 0.f;
#pragma unroll
    for (int j = 0; j < 8; ++j) {
      const float d = x[j] - mu;
      lss += d * d;
    }
    const float var = block_sum(lss, scr) * (1.f / 2048.f);
    const float rstd = rsqrtf(var + 1e-5f);
    const float* lg = ln_g + s * 2048;
    const float* lb = ln_b + s * 2048;
    float nsq = 0.f;
#pragma unroll
    for (int j = 0; j < 8; ++j) {
      const int e = tid * 8 + j;
      const float yv = (x[j] - mu) * rstd * lg[e] + lb[e];
      const float gv = __expf(-yv * yv);
      gbuf[e] = gv;
      nsq += gv * gv;
    }
    const float normsq = block_sum(nsq, scr) + 1e-8f;
    const float factor = sqrtf(2.25f / normsq);
    const float ph = phases[s];
    const float cs = cosf(ph), sn = sinf(ph);
#pragma unroll
    for (int j = 0; j < 4; ++j) {
      const int h = j * 256 + tid;
      const float a = gbuf[h] * factor;
      const float bb = gbuf[h + 1024] * factor;
      wrs[s][h] = a * cs - bb * sn;
      wis[s][h] = a * sn + bb * cs;
    }
    __syncthreads();
  }

  float mr[4];
  float pmn = 0.f;
#pragma unroll
  for (int j = 0; j < 4; ++j) {
    const int h = j * 256 + tid;
    const float m = (wrs[0][h] + wrs[1][h] + wrs[2][h]) * (1.f / 3.f);
    mr[j] = m;
    pmn += m * m;
  }
  const float mnorm = sqrtf(block_sum(pmn, scr)) + 1e-8f;
  float csim[3];
#pragma unroll 1
  for (int s = 0; s < 3; ++s) {
    float pd = 0.f, pw = 0.f;
#pragma unroll
    for (int j = 0; j < 4; ++j) {
      const int h = j * 256 + tid;
      const float w = wrs[s][h];
      pd += w * mr[j];
      pw += w * w;
    }
    const float dot = block_sum(pd, scr);
    const float wn = sqrtf(block_sum(pw, scr)) + 1e-8f;
    csim[s] = dot / (wn * mnorm);
  }
  const float T = temp[0];
  const float t0 = csim[0] / T, t1 = csim[1] / T, t2 = csim[2] / T;
  const float mx = fmaxf(t0, fmaxf(t1, t2));
  const float e0 = __expf(t0 - mx), e1 = __expf(t1 - mx), e2 = __expf(t2 - mx);
  const float inv = 1.f / (e0 + e1 + e2);
  const float w0 = e0 * inv, w1 = e1 * inv, w2 = e2 * inv;
#pragma unroll
  for (int j = 0; j < 4; ++j) {
    const int h = j * 256 + tid;
    supr[(long)(b0 + b) * 1024 + h] = wrs[0][h] * w0 + wrs[1][h] * w1 + wrs[2][h] * w2;
    supi[(long)(b0 + b) * 1024 + h] = wis[0][h] * w0 + wis[1][h] * w1 + wis[2][h] * w2;
  }
}

// ---------------- mag ----------------
__global__ __launch_bounds__(256) void k_mag(const float* __restrict__ sr,
                                             const float* __restrict__ si,
                                             __bf16* __restrict__ mag) {
  const long i = ((long)blockIdx.x * 256 + threadIdx.x) * 4;
  f32x4 r = *(const f32x4*)(sr + i);
  f32x4 im = *(const f32x4*)(si + i);
  bf16x4 o;
#pragma unroll
  for (int j = 0; j < 4; ++j)
    o[j] = (__bf16)sqrtf(r[j] * r[j] + im[j] * im[j] + 1e-8f);
  *(bf16x4*)(mag + i) = o;
}

// ---------------- fused top-8 (u64-key selection) + sparse cls1 ----------------
__global__ __launch_bounds__(256) void k_topk_cls1(
    const float* __restrict__ supr, const float* __restrict__ supi,
    const float* __restrict__ w1t, const float* __restrict__ b1,
    __bf16* __restrict__ hid) {
  __shared__ u64 candk[32];
  __shared__ u64 selk_s[8];
  __shared__ float ssum_s;
  const int tid = threadIdx.x;
  const int lane = tid & 63;
  const int wv = tid >> 6;
  const long b = blockIdx.x;

  f32x4 r = *(const f32x4*)(supr + b * 1024 + tid * 4);
  f32x4 im = *(const f32x4*)(supi + b * 1024 + tid * 4);
  u64 key[4];
#pragma unroll
  for (int j = 0; j < 4; ++j) {
    const float v = r[j] * r[j] + im[j] * im[j];
    key[j] = ((u64)__float_as_uint(v) << 32) | (unsigned)(~(unsigned)(tid * 4 + j));
  }
  u64 lm = key[0];
  int jm = 0;
#pragma unroll
  for (int j = 1; j < 4; ++j)
    if (key[j] > lm) { lm = key[j]; jm = j; }

#pragma unroll 1
  for (int it = 0; it < 8; ++it) {
    u64 bk = lm;
#pragma unroll
    for (int m = 1; m < 64; m <<= 1) {
      const u64 ok = __shfl_xor(bk, m, 64);
      bk = ok > bk ? ok : bk;
    }
    if (lane == 0) candk[wv * 8 + it] = bk;
    if (bk == lm) {
      key[jm] = 0ULL;
      lm = key[0]; jm = 0;
#pragma unroll
      for (int j = 1; j < 4; ++j)
        if (key[j] > lm) { lm = key[j]; jm = j; }
    }
  }
  __syncthreads();

  if (wv == 0) {
    u64 ck = (lane < 32) ? candk[lane] : 0ULL;
    float ss = 0.f;
#pragma unroll 1
    for (int it = 0; it < 8; ++it) {
      u64 bk = ck;
#pragma unroll
      for (int m = 1; m < 64; m <<= 1) {
        const u64 ok = __shfl_xor(bk, m, 64);
        bk = ok > bk ? ok : bk;
      }
      if (ck == bk) ck = 0ULL;
      if (lane == 0) {
        selk_s[it] = bk;
        ss += __uint_as_float((unsigned)(bk >> 32));
      }
    }
    if (lane == 0) ssum_s = ss;
  }
  __syncthreads();

  const float denom = 1.f / (ssum_s + 1e-8f);
  float p[8];
  int idx[8];
#pragma unroll
  for (int k = 0; k < 8; ++k) {
    const u64 kk = selk_s[k];
    p[k] = __uint_as_float((unsigned)(kk >> 32)) * denom;
    idx[k] = (int)(~(unsigned)kk & 1023u);
  }

  const int o0 = tid * 4;
  float acc0 = b1[o0], acc1 = b1[o0 + 1], acc2 = b1[o0 + 2], acc3 = b1[o0 + 3];
#pragma unroll
  for (int k = 0; k < 8; ++k) {
    const f32x4 wrow = *(const f32x4*)(w1t + (long)idx[k] * 1024 + o0);
    acc0 += p[k] * wrow[0];
    acc1 += p[k] * wrow[1];
    acc2 += p[k] * wrow[2];
    acc3 += p[k] * wrow[3];
  }
  bf16x4 o = {(__bf16)gelu_fast(acc0), (__bf16)gelu_fast(acc1),
              (__bf16)gelu_fast(acc2), (__bf16)gelu_fast(acc3)};
  *(bf16x4*)(hid + b * 1024 + o0) = o;
}

extern "C" void kernel_launch(void* const* d_in, const int* in_sizes, int n_in,
                              void* d_out, int out_size, void* d_ws, size_t ws_size,
                              hipStream_t stream) {
  const float* x      = (const float*)d_in[0];
  const float* proj_w = (const float*)d_in[1];
  const float* proj_b = (const float*)d_in[2];
  const float* ln_p_g = (const float*)d_in[3];
  const float* ln_p_b = (const float*)d_in[4];
  const float* wf_w   = (const float*)d_in[5];
  const float* wf_b   = (const float*)d_in[6];
  const float* ln_g   = (const float*)d_in[7];
  const float* ln_b   = (const float*)d_in[8];
  const float* temperature = (const float*)d_in[9];
  const float* phases = (const float*)d_in[10];
  const float* gate_w = (const float*)d_in[11];
  const float* gate_b = (const float*)d_in[12];
  const float* cls_w1 = (const float*)d_in[13];
  const float* cls_b1 = (const float*)d_in[14];
  const float* cls_w2 = (const float*)d_in[15];
  const float* cls_b2 = (const float*)d_in[16];
  float* out = (float*)d_out;
  (void)in_sizes; (void)n_in; (void)out_size;

  char* ws = (char*)d_ws;
  const size_t MB = 1024 * 1024;

  if (ws_size >= 196 * MB) {
    // ---- full layout (196MB) ----
    __bf16* xb   = (__bf16*)(ws + 0);
    float*  supr = (float*)(ws + 0);
    float*  y1   = (float*)(ws + 32 * MB);
    float*  supi = (float*)(ws + 32 * MB);
    __bf16* outb = (__bf16*)(ws + 64 * MB);
    __bf16* magb = (__bf16*)(ws + 64 * MB);
    __bf16* hid  = (__bf16*)(ws + 80 * MB);
    float*  w1t  = (float*)(ws + 96 * MB);
    __bf16* hb   = (__bf16*)(ws + 160 * MB);
    __bf16* wfwb = (__bf16*)(ws + 176 * MB);
    __bf16* gwb  = (__bf16*)(ws + 188 * MB);
    __bf16* c2b  = (__bf16*)(ws + 190 * MB);
    __bf16* w1b  = (__bf16*)(ws + 192 * MB);

    k_cast_bf16<<<16384, 256, 0, stream>>>(x, xb);
    k_cast_bf16<<<2048, 256, 0, stream>>>(proj_w, w1b);
    k_cast_bf16<<<6144, 256, 0, stream>>>(wf_w, wfwb);
    k_cast_bf16<<<1024, 256, 0, stream>>>(gate_w, gwb);
    k_cast_pad<<<1024, 256, 0, stream>>>(cls_w2, c2b, 1000, 1024);

    k_gemm_bt<0, 64><<<dim3(8, 128), 256, 0, stream>>>(xb, w1b, proj_b, y1, 8192, 1024, 2048, 1024, nullptr, nullptr);
    k_ln_gelu<<<8192, 256, 0, stream>>>(y1, ln_p_g, ln_p_b, hb);

    // G2 via 256x256 8-wave deep-prefetch kernel
    k_gemm256_bt<<<dim3(24, 32), 512, 0, stream>>>(hb, wfwb, wf_b, outb, 8192, 6144, 1024);
    k_stage_c<<<8192, 256, 0, stream>>>(outb, ln_g, ln_b, phases, temperature, supr, supi, 0);

    k_transpose1k<<<dim3(32, 32), 256, 0, stream>>>(cls_w1, w1t);
    for (int it = 0; it < 2; ++it) {
      k_mag<<<8192, 256, 0, stream>>>(supr, supi, magb);
      k_gemm_bt<4, 64><<<dim3(8, 128), 256, 0, stream>>>(magb, gwb, gate_b, nullptr, 8192, 1024, 1024, 1024, supr, supi);
    }
    k_topk_cls1<<<8192, 256, 0, stream>>>(supr, supi, w1t, cls_b1, hid);
    k_gemm_bt<0, 64><<<dim3(8, 128), 256, 0, stream>>>(hid, c2b, cls_b2, out, 8192, 1024, 1024, 1000, nullptr, nullptr);
  } else {
    // ---- fallback layout (128MB): proven 4-chunk path ----
    __bf16* xb    = (__bf16*)(ws + 0);
    float*  supr  = (float*)(ws + 0);
    float*  y1    = (float*)(ws + 32 * MB);
    __bf16* outc  = (__bf16*)(ws + 32 * MB);
    __bf16* magb  = (__bf16*)(ws + 32 * MB);
    __bf16* hid   = (__bf16*)(ws + 32 * MB);
    __bf16* w1b   = (__bf16*)(ws + 64 * MB);
    float*  supi  = (float*)(ws + 64 * MB);
    __bf16* wfwb  = (__bf16*)(ws + 96 * MB);
    __bf16* hb    = (__bf16*)(ws + 108 * MB);
    float*  w1t   = (float*)(ws + 108 * MB);
    __bf16* gwb   = (__bf16*)(ws + 124 * MB);
    __bf16* c2b   = (__bf16*)(ws + 126 * MB);

    k_cast_bf16<<<16384, 256, 0, stream>>>(x, xb);
    k_cast_bf16<<<2048, 256, 0, stream>>>(proj_w, w1b);
    k_cast_bf16<<<6144, 256, 0, stream>>>(wf_w, wfwb);
    k_cast_bf16<<<1024, 256, 0, stream>>>(gate_w, gwb);
    k_cast_pad<<<1024, 256, 0, stream>>>(cls_w2, c2b, 1000, 1024);

    k_gemm_bt<0, 64><<<dim3(8, 128), 256, 0, stream>>>(xb, w1b, proj_b, y1, 8192, 1024, 2048, 1024, nullptr, nullptr);
    k_ln_gelu<<<8192, 256, 0, stream>>>(y1, ln_p_g, ln_p_b, hb);

    for (int c = 0; c < 4; ++c) {
      k_gemm_bt<1, 128><<<dim3(48, 16), 256, 0, stream>>>(hb + (size_t)c * 2048 * 1024, wfwb, wf_b,
                                                          outc, 2048, 6144, 1024, 6144, nullptr, nullptr);
      k_stage_c<<<2048, 256, 0, stream>>>(outc, ln_g, ln_b, phases, temperature,
                                          supr, supi, c * 2048);
    }

    k_transpose1k<<<dim3(32, 32), 256, 0, stream>>>(cls_w1, w1t);
    for (int it = 0; it < 2; ++it) {
      k_mag<<<8192, 256, 0, stream>>>(supr, supi, magb);
      k_gemm_bt<4, 64><<<dim3(8, 128), 256, 0, stream>>>(magb, gwb, gate_b, nullptr, 8192, 1024, 1024, 1024, supr, supi);
    }
    k_topk_cls1<<<8192, 256, 0, stream>>>(supr, supi, w1t, cls_b1, hid);
    k_gemm_bt<0, 64><<<dim3(8, 128), 256, 0, stream>>>(hid, c2b, cls_b2, out, 8192, 1024, 1024, 1000, nullptr, nullptr);
  }
}

// Round 9
// 540.027 us; speedup vs baseline: 1.0429x; 1.0429x over previous
//
#include <hip/hip_runtime.h>
#include <cstdint>

typedef __attribute__((ext_vector_type(8))) __bf16 bf16x8;
typedef __attribute__((ext_vector_type(4))) __bf16 bf16x4;
typedef __attribute__((ext_vector_type(4))) float f32x4;
typedef unsigned long long u64;

__device__ __forceinline__ void gld_lds16(const void* g, void* l) {
  __builtin_amdgcn_global_load_lds(
      (const __attribute__((address_space(1))) void*)g,
      (__attribute__((address_space(3))) void*)l, 16, 0, 0);
}

__device__ __forceinline__ float block_sum(float v, float* scr) {
#pragma unroll
  for (int off = 32; off > 0; off >>= 1) v += __shfl_down(v, off, 64);
  const int w = threadIdx.x >> 6;
  __syncthreads();
  if ((threadIdx.x & 63) == 0) scr[w] = v;
  __syncthreads();
  float s = 0.f;
  const int nw = blockDim.x >> 6;
  for (int i = 0; i < nw; ++i) s += scr[i];
  return s;
}

// fast gelu: A&S 7.1.26 erf (|err|<1.5e-7) + hw exp
__device__ __forceinline__ float gelu_fast(float x) {
  const float ax = fabsf(x) * 0.70710678118654752f;
  const float t = 1.f / (1.f + 0.3275911f * ax);
  const float e = __expf(-ax * ax);
  float poly = 1.061405429f;
  poly = poly * t - 1.453152027f;
  poly = poly * t + 1.421413741f;
  poly = poly * t - 0.284496736f;
  poly = poly * t + 0.254829592f;
  const float erfax = 1.f - poly * t * e;
  const float er = copysignf(erfax, x);
  return 0.5f * x * (1.f + er);
}

// ---------------- casts ----------------
__global__ __launch_bounds__(256) void k_cast_bf16(const float* __restrict__ in,
                                                   __bf16* __restrict__ out) {
  const long i = ((long)blockIdx.x * 256 + threadIdx.x) * 4;
  f32x4 v = *(const f32x4*)(in + i);
  bf16x4 o = {(__bf16)v[0], (__bf16)v[1], (__bf16)v[2], (__bf16)v[3]};
  *(bf16x4*)(out + i) = o;
}

__global__ __launch_bounds__(256) void k_cast_pad(const float* __restrict__ in,
                                                  __bf16* __restrict__ out,
                                                  int rows_real, int cols) {
  const long i = ((long)blockIdx.x * 256 + threadIdx.x) * 4;
  const int row = (int)(i / cols);
  const int col = (int)(i % cols);
  bf16x4 o;
  if (row < rows_real) {
    f32x4 v = *(const f32x4*)(in + (long)row * cols + col);
    o = (bf16x4){(__bf16)v[0], (__bf16)v[1], (__bf16)v[2], (__bf16)v[3]};
  } else {
    o = (bf16x4){(__bf16)0.f, (__bf16)0.f, (__bf16)0.f, (__bf16)0.f};
  }
  *(bf16x4*)(out + i) = o;
}

// ---------------- transpose 1024x1024 f32 ----------------
__global__ __launch_bounds__(256) void k_transpose1k(const float* __restrict__ in,
                                                     float* __restrict__ out) {
  __shared__ float t[32][33];
  const int tx = threadIdx.x & 31;
  const int ty = threadIdx.x >> 5;
  const int r0 = blockIdx.y * 32, c0 = blockIdx.x * 32;
#pragma unroll
  for (int k = 0; k < 4; ++k)
    t[ty + 8 * k][tx] = in[(long)(r0 + ty + 8 * k) * 1024 + c0 + tx];
  __syncthreads();
#pragma unroll
  for (int k = 0; k < 4; ++k)
    out[(long)(c0 + ty + 8 * k) * 1024 + r0 + tx] = t[tx][ty + 8 * k];
}

// ============ 256x256 8-wave BK=64 GEMM, 2-barrier big region (bf16 out) ============
// Counted vmcnt(8) deep prefetch; per-tile region = [stage next; vmcnt(8);
// barrier; reads+MFMA free-run; barrier]. XOR bank-swizzle both sides,
// setprio, bijective XCD swizzle.
__global__ __launch_bounds__(512, 1) void k_gemm256_bt(
    const __bf16* __restrict__ A, const __bf16* __restrict__ B,
    const float* __restrict__ bias, __bf16* __restrict__ C,
    int M, int N, int K) {
  __shared__ __align__(16) __bf16 lds[2][2][256 * 64];  // [slot][mat][row*64+k]
  const int tid = threadIdx.x;
  const int lane = tid & 63;
  const int wid = tid >> 6;
  const int wr = wid >> 2;   // 0..1 : 128-row group
  const int wc = wid & 3;    // 0..3 : 64-col group
  const int gx = gridDim.x, gy = gridDim.y;
  const int nwg = gx * gy;
  const int lin = blockIdx.y * gx + blockIdx.x;
  const int cpx = nwg >> 3;  // nwg % 8 == 0 by construction
  const int wsw = (lin & 7) * cpx + (lin >> 3);
  const int bx = wsw / gy, by = wsw % gy;
  const int m0 = by * 256, n0 = bx * 256;
  const int fr = lane & 15;  // fragment row
  const int fx = lane >> 4;  // 0..3 : k-subgroup
  const int px = lane & 7;   // read-side swizzle key (== row&7 for all frags)

  const __bf16* Abase = A + (long)m0 * K;
  const __bf16* Bbase = B + (long)n0 * K;

  auto stage_q = [&](int slot, int kt, int mat, int half) {
    const __bf16* src = (mat ? Bbase : Abase) + kt * 64;
#pragma unroll
    for (int q = 0; q < 2; ++q) {
      const int idx = q * 512 + tid;   // [0,1024)
      const int r = idx >> 3;          // 0..127
      const int pblk = idx & 7;        // 16B block within 128B row
      const int row = half * 128 + r;
      const int lblk = pblk ^ (r & 7); // involution
      gld_lds16(src + (long)row * K + lblk * 8,
                (char*)&lds[slot][mat][row * 64 + pblk * 8]);
    }
  };
  auto frag = [&](int slot, int mat, int row, int ks) -> bf16x8 {
    return *(const bf16x8*)&lds[slot][mat][row * 64 + ((((ks << 2) + fx) ^ px) << 3)];
  };

  f32x4 acc[8][4] = {};
  const int nt = K >> 6;
#pragma unroll
  for (int qp = 0; qp < 4; ++qp) stage_q(0, 0, qp >> 1, qp & 1);

  const int arow = wr * 128 + fr;
  const int brow = wc * 64 + fr;

  for (int t = 0; t < nt; ++t) {
    const int sc = t & 1, sn = sc ^ 1;
    if (t + 1 < nt) {
#pragma unroll
      for (int qp = 0; qp < 4; ++qp) stage_q(sn, t + 1, qp >> 1, qp & 1);
      asm volatile("s_waitcnt vmcnt(8)" ::: "memory");
    } else {
      asm volatile("s_waitcnt vmcnt(0)" ::: "memory");
    }
    __builtin_amdgcn_sched_barrier(0);
    __builtin_amdgcn_s_barrier();  // publish slot sc across waves
    bf16x8 b0[4], b1[4];
#pragma unroll
    for (int j = 0; j < 4; ++j) {
      b0[j] = frag(sc, 1, brow + j * 16, 0);
      b1[j] = frag(sc, 1, brow + j * 16, 1);
    }
    __builtin_amdgcn_s_setprio(1);
#pragma unroll
    for (int im = 0; im < 8; ++im) {
      bf16x8 x0 = frag(sc, 0, arow + im * 16, 0);
      bf16x8 x1 = frag(sc, 0, arow + im * 16, 1);
#pragma unroll
      for (int j = 0; j < 4; ++j) {
        acc[im][j] = __builtin_amdgcn_mfma_f32_16x16x32_bf16(x0, b0[j], acc[im][j], 0, 0, 0);
        acc[im][j] = __builtin_amdgcn_mfma_f32_16x16x32_bf16(x1, b1[j], acc[im][j], 0, 0, 0);
      }
    }
    __builtin_amdgcn_s_setprio(0);
    __builtin_amdgcn_s_barrier();  // all waves done reading sc
  }

  const int crow0 = m0 + wr * 128 + fx * 4;
  const int ccol0 = n0 + wc * 64 + fr;
#pragma unroll
  for (int j = 0; j < 4; ++j) {
    const int col = ccol0 + j * 16;
    const float bv = bias[col];
#pragma unroll
    for (int im = 0; im < 8; ++im)
#pragma unroll
      for (int r = 0; r < 4; ++r)
        C[(long)(crow0 + im * 16 + r) * N + col] = (__bf16)(acc[im][j][r] + bv);
  }
}

// ---------------- GEMM: C = A @ B^T + bias (128-col tiles) ----------------
// EPI: 0 f32, 1 bf16, 4 fused self-mod update, 5 = update + mag-out
template <int EPI, int BM>
__global__ __launch_bounds__(256) void k_gemm_bt(
    const __bf16* __restrict__ A, const __bf16* __restrict__ B,
    const float* __restrict__ bias, void* __restrict__ Cout,
    int M, int N, int K, int Nreal,
    float* __restrict__ supR, float* __restrict__ supI,
    __bf16* __restrict__ magOut) {
  constexpr int MR = BM / 32;
  __shared__ __align__(16) __bf16 As[2][BM * 32];
  __shared__ __align__(16) __bf16 Bs[2][128 * 32];
  const int tid = threadIdx.x;
  const int lane = tid & 63;
  const int wid = tid >> 6;
  const int wr = wid >> 1, wc = wid & 1;

  const int gx = gridDim.x, gy = gridDim.y;
  const int nwg = gx * gy;
  int bx, by;
  if ((nwg & 7) == 0) {
    const int lin = blockIdx.y * gx + blockIdx.x;
    const int cpx = nwg >> 3;
    const int w = (lin & 7) * cpx + (lin >> 3);
    bx = w / gy;
    by = w % gy;
  } else {
    bx = blockIdx.x;
    by = blockIdx.y;
  }
  const int m0 = by * BM;
  const int n0 = bx * 128;
  const int frow = lane & 15;
  const int fk = (lane >> 4) * 8;
  f32x4 acc[MR][4] = {};

  auto stage = [&](int buf, int k0) {
    const __bf16* Ab = A + (long)m0 * K + k0;
    const __bf16* Bb = B + (long)n0 * K + k0;
#pragma unroll
    for (int q = 0; q < BM / 64; ++q) {
      const int idx = q * 256 + tid;
      const int row = idx >> 2;
      const int col = (idx & 3) * 8;
      gld_lds16(Ab + (long)row * K + col, (char*)(&As[buf][0]) + idx * 16);
    }
#pragma unroll
    for (int q = 0; q < 2; ++q) {
      const int idx = q * 256 + tid;
      const int row = idx >> 2;
      const int col = (idx & 3) * 8;
      gld_lds16(Bb + (long)row * K + col, (char*)(&Bs[buf][0]) + idx * 16);
    }
  };

  const int nt = K >> 5;
  int cur = 0;
  stage(0, 0);
  __syncthreads();
  for (int t = 0; t < nt; ++t) {
    if (t + 1 < nt) stage(cur ^ 1, (t + 1) << 5);
    bf16x8 af[MR], bfr[4];
#pragma unroll
    for (int i = 0; i < MR; ++i)
      af[i] = *(const bf16x8*)(&As[cur][0] + (wr * (BM / 2) + i * 16 + frow) * 32 + fk);
#pragma unroll
    for (int i = 0; i < 4; ++i)
      bfr[i] = *(const bf16x8*)(&Bs[cur][0] + (wc * 64 + i * 16 + frow) * 32 + fk);
#pragma unroll
    for (int im = 0; im < MR; ++im)
#pragma unroll
      for (int in = 0; in < 4; ++in)
        acc[im][in] = __builtin_amdgcn_mfma_f32_16x16x32_bf16(af[im], bfr[in],
                                                              acc[im][in], 0, 0, 0);
    __syncthreads();
    cur ^= 1;
  }

  const int crow0 = m0 + wr * (BM / 2) + (lane >> 4) * 4;
  const int ccol0 = n0 + wc * 64 + (lane & 15);
#pragma unroll
  for (int in = 0; in < 4; ++in) {
    const int col = ccol0 + in * 16;
    if (col >= Nreal) continue;
    const float bv = bias[col];
#pragma unroll
    for (int im = 0; im < MR; ++im) {
#pragma unroll
      for (int r = 0; r < 4; ++r) {
        const long row = crow0 + im * 16 + r;
        const float v = acc[im][in][r] + bv;
        if (EPI == 0) {
          ((float*)Cout)[row * Nreal + col] = v;
        } else if (EPI == 1) {
          ((__bf16*)Cout)[row * Nreal + col] = (__bf16)v;
        } else {
          const float gmul = 1.f / (1.f + __expf(-v)) + 0.1f;
          const long ix = row * Nreal + col;
          const float nr = supR[ix] * gmul;
          const float ni = supI[ix] * gmul;
          supR[ix] = nr;
          supI[ix] = ni;
          if (EPI == 5) magOut[ix] = (__bf16)sqrtf(nr * nr + ni * ni + 1e-8f);
        }
      }
    }
  }
}

// ---------------- LN (over 1024) + gelu -> bf16 ----------------
__global__ __launch_bounds__(256) void k_ln_gelu(const float* __restrict__ y,
                                                 const float* __restrict__ g,
                                                 const float* __restrict__ b,
                                                 __bf16* __restrict__ h) {
  __shared__ float scr[8];
  const int tid = threadIdx.x;
  const long row = blockIdx.x;
  const float* yr = y + row * 1024;
  f32x4 v = *(const f32x4*)(yr + tid * 4);
  float ls = v[0] + v[1] + v[2] + v[3];
  const float mu = block_sum(ls, scr) * (1.f / 1024.f);
  float lss = 0.f;
#pragma unroll
  for (int j = 0; j < 4; ++j) {
    const float d = v[j] - mu;
    lss += d * d;
  }
  const float var = block_sum(lss, scr) * (1.f / 1024.f);
  const float rstd = rsqrtf(var + 1e-5f);
  bf16x4 o;
#pragma unroll
  for (int j = 0; j < 4; ++j) {
    const int c = tid * 4 + j;
    const float t = (v[j] - mu) * rstd * g[c] + b[c];
    o[j] = (__bf16)gelu_fast(t);
  }
  *(bf16x4*)(h + row * 1024 + tid * 4) = o;
}

// ---------------- stage C (optionally fused mag output) ----------------
__global__ __launch_bounds__(256) void k_stage_c(
    const __bf16* __restrict__ outb, const float* __restrict__ ln_g,
    const float* __restrict__ ln_b, const float* __restrict__ phases,
    const float* __restrict__ temp, float* __restrict__ supr,
    float* __restrict__ supi, __bf16* __restrict__ magp, int b0) {
  __shared__ float wrs[3][1024];
  __shared__ float wis[3][1024];
  __shared__ float gbuf[2048];
  __shared__ float scr[8];
  const int tid = threadIdx.x;
  const long b = blockIdx.x;

#pragma unroll 1
  for (int s = 0; s < 3; ++s) {
    const __bf16* src = outb + b * 6144 + s * 2048;
    bf16x8 v8 = *(const bf16x8*)(src + tid * 8);
    float x[8];
#pragma unroll
    for (int j = 0; j < 8; ++j) x[j] = (float)v8[j];
    float ls = 0.f;
#pragma unroll
    for (int j = 0; j < 8; ++j) ls += x[j];
    const float mu = block_sum(ls, scr) * (1.f / 2048.f);
    float lss = 0.f;
#pragma unroll
    for (int j = 0; j < 8; ++j) {
      const float d = x[j] - mu;
      lss += d * d;
    }
    const float var = block_sum(lss, scr) * (1.f / 2048.f);
    const float rstd = rsqrtf(var + 1e-5f);
    const float* lg = ln_g + s * 2048;
    const float* lb = ln_b + s * 2048;
    float nsq = 0.f;
#pragma unroll
    for (int j = 0; j < 8; ++j) {
      const int e = tid * 8 + j;
      const float yv = (x[j] - mu) * rstd * lg[e] + lb[e];
      const float gv = __expf(-yv * yv);
      gbuf[e] = gv;
      nsq += gv * gv;
    }
    const float normsq = block_sum(nsq, scr) + 1e-8f;
    const float factor = sqrtf(2.25f / normsq);
    const float ph = phases[s];
    const float cs = cosf(ph), sn = sinf(ph);
#pragma unroll
    for (int j = 0; j < 4; ++j) {
      const int h = j * 256 + tid;
      const float a = gbuf[h] * factor;
      const float bb = gbuf[h + 1024] * factor;
      wrs[s][h] = a * cs - bb * sn;
      wis[s][h] = a * sn + bb * cs;
    }
    __syncthreads();
  }

  float mr[4];
  float pmn = 0.f;
#pragma unroll
  for (int j = 0; j < 4; ++j) {
    const int h = j * 256 + tid;
    const float m = (wrs[0][h] + wrs[1][h] + wrs[2][h]) * (1.f / 3.f);
    mr[j] = m;
    pmn += m * m;
  }
  const float mnorm = sqrtf(block_sum(pmn, scr)) + 1e-8f;
  float csim[3];
#pragma unroll 1
  for (int s = 0; s < 3; ++s) {
    float pd = 0.f, pw = 0.f;
#pragma unroll
    for (int j = 0; j < 4; ++j) {
      const int h = j * 256 + tid;
      const float w = wrs[s][h];
      pd += w * mr[j];
      pw += w * w;
    }
    const float dot = block_sum(pd, scr);
    const float wn = sqrtf(block_sum(pw, scr)) + 1e-8f;
    csim[s] = dot / (wn * mnorm);
  }
  const float T = temp[0];
  const float t0 = csim[0] / T, t1 = csim[1] / T, t2 = csim[2] / T;
  const float mx = fmaxf(t0, fmaxf(t1, t2));
  const float e0 = __expf(t0 - mx), e1 = __expf(t1 - mx), e2 = __expf(t2 - mx);
  const float inv = 1.f / (e0 + e1 + e2);
  const float w0 = e0 * inv, w1 = e1 * inv, w2 = e2 * inv;
#pragma unroll
  for (int j = 0; j < 4; ++j) {
    const int h = j * 256 + tid;
    const float sr = wrs[0][h] * w0 + wrs[1][h] * w1 + wrs[2][h] * w2;
    const float si = wis[0][h] * w0 + wis[1][h] * w1 + wis[2][h] * w2;
    supr[(long)(b0 + b) * 1024 + h] = sr;
    supi[(long)(b0 + b) * 1024 + h] = si;
    if (magp) magp[(long)(b0 + b) * 1024 + h] = (__bf16)sqrtf(sr * sr + si * si + 1e-8f);
  }
}

// ---------------- mag (fallback path only) ----------------
__global__ __launch_bounds__(256) void k_mag(const float* __restrict__ sr,
                                             const float* __restrict__ si,
                                             __bf16* __restrict__ mag) {
  const long i = ((long)blockIdx.x * 256 + threadIdx.x) * 4;
  f32x4 r = *(const f32x4*)(sr + i);
  f32x4 im = *(const f32x4*)(si + i);
  bf16x4 o;
#pragma unroll
  for (int j = 0; j < 4; ++j)
    o[j] = (__bf16)sqrtf(r[j] * r[j] + im[j] * im[j] + 1e-8f);
  *(bf16x4*)(mag + i) = o;
}

// ---------------- fused top-8 (u64-key selection) + sparse cls1 ----------------
__global__ __launch_bounds__(256) void k_topk_cls1(
    const float* __restrict__ supr, const float* __restrict__ supi,
    const float* __restrict__ w1t, const float* __restrict__ b1,
    __bf16* __restrict__ hid) {
  __shared__ u64 candk[32];
  __shared__ u64 selk_s[8];
  __shared__ float ssum_s;
  const int tid = threadIdx.x;
  const int lane = tid & 63;
  const int wv = tid >> 6;
  const long b = blockIdx.x;

  f32x4 r = *(const f32x4*)(supr + b * 1024 + tid * 4);
  f32x4 im = *(const f32x4*)(supi + b * 1024 + tid * 4);
  u64 key[4];
#pragma unroll
  for (int j = 0; j < 4; ++j) {
    const float v = r[j] * r[j] + im[j] * im[j];
    key[j] = ((u64)__float_as_uint(v) << 32) | (unsigned)(~(unsigned)(tid * 4 + j));
  }
  u64 lm = key[0];
  int jm = 0;
#pragma unroll
  for (int j = 1; j < 4; ++j)
    if (key[j] > lm) { lm = key[j]; jm = j; }

#pragma unroll 1
  for (int it = 0; it < 8; ++it) {
    u64 bk = lm;
#pragma unroll
    for (int m = 1; m < 64; m <<= 1) {
      const u64 ok = __shfl_xor(bk, m, 64);
      bk = ok > bk ? ok : bk;
    }
    if (lane == 0) candk[wv * 8 + it] = bk;
    if (bk == lm) {
      key[jm] = 0ULL;
      lm = key[0]; jm = 0;
#pragma unroll
      for (int j = 1; j < 4; ++j)
        if (key[j] > lm) { lm = key[j]; jm = j; }
    }
  }
  __syncthreads();

  if (wv == 0) {
    u64 ck = (lane < 32) ? candk[lane] : 0ULL;
    float ss = 0.f;
#pragma unroll 1
    for (int it = 0; it < 8; ++it) {
      u64 bk = ck;
#pragma unroll
      for (int m = 1; m < 64; m <<= 1) {
        const u64 ok = __shfl_xor(bk, m, 64);
        bk = ok > bk ? ok : bk;
      }
      if (ck == bk) ck = 0ULL;
      if (lane == 0) {
        selk_s[it] = bk;
        ss += __uint_as_float((unsigned)(bk >> 32));
      }
    }
    if (lane == 0) ssum_s = ss;
  }
  __syncthreads();

  const float denom = 1.f / (ssum_s + 1e-8f);
  float p[8];
  int idx[8];
#pragma unroll
  for (int k = 0; k < 8; ++k) {
    const u64 kk = selk_s[k];
    p[k] = __uint_as_float((unsigned)(kk >> 32)) * denom;
    idx[k] = (int)(~(unsigned)kk & 1023u);
  }

  const int o0 = tid * 4;
  float acc0 = b1[o0], acc1 = b1[o0 + 1], acc2 = b1[o0 + 2], acc3 = b1[o0 + 3];
#pragma unroll
  for (int k = 0; k < 8; ++k) {
    const f32x4 wrow = *(const f32x4*)(w1t + (long)idx[k] * 1024 + o0);
    acc0 += p[k] * wrow[0];
    acc1 += p[k] * wrow[1];
    acc2 += p[k] * wrow[2];
    acc3 += p[k] * wrow[3];
  }
  bf16x4 o = {(__bf16)gelu_fast(acc0), (__bf16)gelu_fast(acc1),
              (__bf16)gelu_fast(acc2), (__bf16)gelu_fast(acc3)};
  *(bf16x4*)(hid + b * 1024 + o0) = o;
}

extern "C" void kernel_launch(void* const* d_in, const int* in_sizes, int n_in,
                              void* d_out, int out_size, void* d_ws, size_t ws_size,
                              hipStream_t stream) {
  const float* x      = (const float*)d_in[0];
  const float* proj_w = (const float*)d_in[1];
  const float* proj_b = (const float*)d_in[2];
  const float* ln_p_g = (const float*)d_in[3];
  const float* ln_p_b = (const float*)d_in[4];
  const float* wf_w   = (const float*)d_in[5];
  const float* wf_b   = (const float*)d_in[6];
  const float* ln_g   = (const float*)d_in[7];
  const float* ln_b   = (const float*)d_in[8];
  const float* temperature = (const float*)d_in[9];
  const float* phases = (const float*)d_in[10];
  const float* gate_w = (const float*)d_in[11];
  const float* gate_b = (const float*)d_in[12];
  const float* cls_w1 = (const float*)d_in[13];
  const float* cls_b1 = (const float*)d_in[14];
  const float* cls_w2 = (const float*)d_in[15];
  const float* cls_b2 = (const float*)d_in[16];
  float* out = (float*)d_out;
  (void)in_sizes; (void)n_in; (void)out_size;

  char* ws = (char*)d_ws;
  const size_t MB = 1024 * 1024;

  if (ws_size >= 196 * MB) {
    // ---- full layout (196MB) ----
    //  [0,32): xb -> supr        [32,64): y1 -> supi
    //  [64,160): outb (dead after stage_c) -> { magb2@64, hid@80, w1t@96 }
    //  [160,176): hb (dead after G2) -> magb
    //  [176,188): wfwb  [188,190): gwb  [190,192): c2b  [192,196): w1b
    __bf16* xb    = (__bf16*)(ws + 0);
    float*  supr  = (float*)(ws + 0);
    float*  y1    = (float*)(ws + 32 * MB);
    float*  supi  = (float*)(ws + 32 * MB);
    __bf16* outb  = (__bf16*)(ws + 64 * MB);
    __bf16* magb2 = (__bf16*)(ws + 64 * MB);
    __bf16* hid   = (__bf16*)(ws + 80 * MB);
    float*  w1t   = (float*)(ws + 96 * MB);
    __bf16* hb    = (__bf16*)(ws + 160 * MB);
    __bf16* magb  = (__bf16*)(ws + 160 * MB);
    __bf16* wfwb  = (__bf16*)(ws + 176 * MB);
    __bf16* gwb   = (__bf16*)(ws + 188 * MB);
    __bf16* c2b   = (__bf16*)(ws + 190 * MB);
    __bf16* w1b   = (__bf16*)(ws + 192 * MB);

    k_cast_bf16<<<16384, 256, 0, stream>>>(x, xb);
    k_cast_bf16<<<2048, 256, 0, stream>>>(proj_w, w1b);
    k_cast_bf16<<<6144, 256, 0, stream>>>(wf_w, wfwb);
    k_cast_bf16<<<1024, 256, 0, stream>>>(gate_w, gwb);
    k_cast_pad<<<1024, 256, 0, stream>>>(cls_w2, c2b, 1000, 1024);

    k_gemm_bt<0, 64><<<dim3(8, 128), 256, 0, stream>>>(xb, w1b, proj_b, y1, 8192, 1024, 2048, 1024, nullptr, nullptr, nullptr);
    k_ln_gelu<<<8192, 256, 0, stream>>>(y1, ln_p_g, ln_p_b, hb);

    // G2 via 256x256 2-barrier big-region kernel
    k_gemm256_bt<<<dim3(24, 32), 512, 0, stream>>>(hb, wfwb, wf_b, outb, 8192, 6144, 1024);
    // stage_c with fused mag0 -> magb (hb region, dead now)
    k_stage_c<<<8192, 256, 0, stream>>>(outb, ln_g, ln_b, phases, temperature, supr, supi, magb, 0);

    k_transpose1k<<<dim3(32, 32), 256, 0, stream>>>(cls_w1, w1t);
    // self-mod iter0: update + write mag1 -> magb2 ; iter1: update only
    k_gemm_bt<5, 64><<<dim3(8, 128), 256, 0, stream>>>(magb, gwb, gate_b, nullptr, 8192, 1024, 1024, 1024, supr, supi, magb2);
    k_gemm_bt<4, 64><<<dim3(8, 128), 256, 0, stream>>>(magb2, gwb, gate_b, nullptr, 8192, 1024, 1024, 1024, supr, supi, nullptr);

    k_topk_cls1<<<8192, 256, 0, stream>>>(supr, supi, w1t, cls_b1, hid);
    k_gemm_bt<0, 64><<<dim3(8, 128), 256, 0, stream>>>(hid, c2b, cls_b2, out, 8192, 1024, 1024, 1000, nullptr, nullptr, nullptr);
  } else {
    // ---- fallback layout (128MB): proven 4-chunk path ----
    __bf16* xb    = (__bf16*)(ws + 0);
    float*  supr  = (float*)(ws + 0);
    float*  y1    = (float*)(ws + 32 * MB);
    __bf16* outc  = (__bf16*)(ws + 32 * MB);
    __bf16* magb  = (__bf16*)(ws + 32 * MB);
    __bf16* hid   = (__bf16*)(ws + 32 * MB);
    __bf16* w1b   = (__bf16*)(ws + 64 * MB);
    float*  supi  = (float*)(ws + 64 * MB);
    __bf16* wfwb  = (__bf16*)(ws + 96 * MB);
    __bf16* hb    = (__bf16*)(ws + 108 * MB);
    float*  w1t   = (float*)(ws + 108 * MB);
    __bf16* gwb   = (__bf16*)(ws + 124 * MB);
    __bf16* c2b   = (__bf16*)(ws + 126 * MB);

    k_cast_bf16<<<16384, 256, 0, stream>>>(x, xb);
    k_cast_bf16<<<2048, 256, 0, stream>>>(proj_w, w1b);
    k_cast_bf16<<<6144, 256, 0, stream>>>(wf_w, wfwb);
    k_cast_bf16<<<1024, 256, 0, stream>>>(gate_w, gwb);
    k_cast_pad<<<1024, 256, 0, stream>>>(cls_w2, c2b, 1000, 1024);

    k_gemm_bt<0, 64><<<dim3(8, 128), 256, 0, stream>>>(xb, w1b, proj_b, y1, 8192, 1024, 2048, 1024, nullptr, nullptr, nullptr);
    k_ln_gelu<<<8192, 256, 0, stream>>>(y1, ln_p_g, ln_p_b, hb);

    for (int c = 0; c < 4; ++c) {
      k_gemm_bt<1, 128><<<dim3(48, 16), 256, 0, stream>>>(hb + (size_t)c * 2048 * 1024, wfwb, wf_b,
                                                          outc, 2048, 6144, 1024, 6144, nullptr, nullptr, nullptr);
      k_stage_c<<<2048, 256, 0, stream>>>(outc, ln_g, ln_b, phases, temperature,
                                          supr, supi, nullptr, c * 2048);
    }

    k_transpose1k<<<dim3(32, 32), 256, 0, stream>>>(cls_w1, w1t);
    for (int it = 0; it < 2; ++it) {
      k_mag<<<8192, 256, 0, stream>>>(supr, supi, magb);
      k_gemm_bt<4, 64><<<dim3(8, 128), 256, 0, stream>>>(magb, gwb, gate_b, nullptr, 8192, 1024, 1024, 1024, supr, supi, nullptr);
    }
    k_topk_cls1<<<8192, 256, 0, stream>>>(supr, supi, w1t, cls_b1, hid);
    k_gemm_bt<0, 64><<<dim3(8, 128), 256, 0, stream>>>(hid, c2b, cls_b2, out, 8192, 1024, 1024, 1000, nullptr, nullptr, nullptr);
  }
}

// Round 10
// 504.745 us; speedup vs baseline: 1.1158x; 1.0699x over previous
//
#include <hip/hip_runtime.h>
#include <cstdint>

typedef __attribute__((ext_vector_type(8))) __bf16 bf16x8;
typedef __attribute__((ext_vector_type(4))) __bf16 bf16x4;
typedef __attribute__((ext_vector_type(4))) float f32x4;
typedef unsigned long long u64;

__device__ __forceinline__ void gld_lds16(const void* g, void* l) {
  __builtin_amdgcn_global_load_lds(
      (const __attribute__((address_space(1))) void*)g,
      (__attribute__((address_space(3))) void*)l, 16, 0, 0);
}

__device__ __forceinline__ float block_sum(float v, float* scr) {
#pragma unroll
  for (int off = 32; off > 0; off >>= 1) v += __shfl_down(v, off, 64);
  const int w = threadIdx.x >> 6;
  __syncthreads();
  if ((threadIdx.x & 63) == 0) scr[w] = v;
  __syncthreads();
  float s = 0.f;
  const int nw = blockDim.x >> 6;
  for (int i = 0; i < nw; ++i) s += scr[i];
  return s;
}

// fast gelu: A&S 7.1.26 erf (|err|<1.5e-7) + hw exp
__device__ __forceinline__ float gelu_fast(float x) {
  const float ax = fabsf(x) * 0.70710678118654752f;
  const float t = 1.f / (1.f + 0.3275911f * ax);
  const float e = __expf(-ax * ax);
  float poly = 1.061405429f;
  poly = poly * t - 1.453152027f;
  poly = poly * t + 1.421413741f;
  poly = poly * t - 0.284496736f;
  poly = poly * t + 0.254829592f;
  const float erfax = 1.f - poly * t * e;
  const float er = copysignf(erfax, x);
  return 0.5f * x * (1.f + er);
}

// ---------------- casts ----------------
__global__ __launch_bounds__(256) void k_cast_bf16(const float* __restrict__ in,
                                                   __bf16* __restrict__ out) {
  const long i = ((long)blockIdx.x * 256 + threadIdx.x) * 4;
  f32x4 v = *(const f32x4*)(in + i);
  bf16x4 o = {(__bf16)v[0], (__bf16)v[1], (__bf16)v[2], (__bf16)v[3]};
  *(bf16x4*)(out + i) = o;
}

// combined weight casts: proj_w(2048 blk) | wf_w(6144 blk) | gate_w(1024 blk)
__global__ __launch_bounds__(256) void k_cast_weights(
    const float* __restrict__ pw, __bf16* __restrict__ w1b,
    const float* __restrict__ wfw, __bf16* __restrict__ wfwb,
    const float* __restrict__ gw, __bf16* __restrict__ gwb) {
  const int bid = blockIdx.x;
  const float* in;
  __bf16* out;
  long base;
  if (bid < 2048) { in = pw; out = w1b; base = (long)bid * 1024; }
  else if (bid < 8192) { in = wfw; out = wfwb; base = (long)(bid - 2048) * 1024; }
  else { in = gw; out = gwb; base = (long)(bid - 8192) * 1024; }
  const long i = base + threadIdx.x * 4;
  f32x4 v = *(const f32x4*)(in + i);
  bf16x4 o = {(__bf16)v[0], (__bf16)v[1], (__bf16)v[2], (__bf16)v[3]};
  *(bf16x4*)(out + i) = o;
}

__global__ __launch_bounds__(256) void k_cast_pad(const float* __restrict__ in,
                                                  __bf16* __restrict__ out,
                                                  int rows_real, int cols) {
  const long i = ((long)blockIdx.x * 256 + threadIdx.x) * 4;
  const int row = (int)(i / cols);
  const int col = (int)(i % cols);
  bf16x4 o;
  if (row < rows_real) {
    f32x4 v = *(const f32x4*)(in + (long)row * cols + col);
    o = (bf16x4){(__bf16)v[0], (__bf16)v[1], (__bf16)v[2], (__bf16)v[3]};
  } else {
    o = (bf16x4){(__bf16)0.f, (__bf16)0.f, (__bf16)0.f, (__bf16)0.f};
  }
  *(bf16x4*)(out + i) = o;
}

// ---------------- transpose 1024x1024 f32 ----------------
__global__ __launch_bounds__(256) void k_transpose1k(const float* __restrict__ in,
                                                     float* __restrict__ out) {
  __shared__ float t[32][33];
  const int tx = threadIdx.x & 31;
  const int ty = threadIdx.x >> 5;
  const int r0 = blockIdx.y * 32, c0 = blockIdx.x * 32;
#pragma unroll
  for (int k = 0; k < 4; ++k)
    t[ty + 8 * k][tx] = in[(long)(r0 + ty + 8 * k) * 1024 + c0 + tx];
  __syncthreads();
#pragma unroll
  for (int k = 0; k < 4; ++k)
    out[(long)(c0 + ty + 8 * k) * 1024 + r0 + tx] = t[tx][ty + 8 * k];
}

// ============ 256x256 8-wave BK=64 GEMM, 2-barrier big region (bf16 out) ============
__global__ __launch_bounds__(512, 1) void k_gemm256_bt(
    const __bf16* __restrict__ A, const __bf16* __restrict__ B,
    const float* __restrict__ bias, __bf16* __restrict__ C,
    int M, int N, int K) {
  __shared__ __align__(16) __bf16 lds[2][2][256 * 64];  // [slot][mat][row*64+k]
  const int tid = threadIdx.x;
  const int lane = tid & 63;
  const int wid = tid >> 6;
  const int wr = wid >> 2;
  const int wc = wid & 3;
  const int gx = gridDim.x, gy = gridDim.y;
  const int nwg = gx * gy;
  const int lin = blockIdx.y * gx + blockIdx.x;
  const int cpx = nwg >> 3;
  const int wsw = (lin & 7) * cpx + (lin >> 3);
  const int bx = wsw / gy, by = wsw % gy;
  const int m0 = by * 256, n0 = bx * 256;
  const int fr = lane & 15;
  const int fx = lane >> 4;
  const int px = lane & 7;

  const __bf16* Abase = A + (long)m0 * K;
  const __bf16* Bbase = B + (long)n0 * K;

  auto stage_q = [&](int slot, int kt, int mat, int half) {
    const __bf16* src = (mat ? Bbase : Abase) + kt * 64;
#pragma unroll
    for (int q = 0; q < 2; ++q) {
      const int idx = q * 512 + tid;
      const int r = idx >> 3;
      const int pblk = idx & 7;
      const int row = half * 128 + r;
      const int lblk = pblk ^ (r & 7);
      gld_lds16(src + (long)row * K + lblk * 8,
                (char*)&lds[slot][mat][row * 64 + pblk * 8]);
    }
  };
  auto frag = [&](int slot, int mat, int row, int ks) -> bf16x8 {
    return *(const bf16x8*)&lds[slot][mat][row * 64 + ((((ks << 2) + fx) ^ px) << 3)];
  };

  f32x4 acc[8][4] = {};
  const int nt = K >> 6;
#pragma unroll
  for (int qp = 0; qp < 4; ++qp) stage_q(0, 0, qp >> 1, qp & 1);

  const int arow = wr * 128 + fr;
  const int brow = wc * 64 + fr;

  for (int t = 0; t < nt; ++t) {
    const int sc = t & 1, sn = sc ^ 1;
    if (t + 1 < nt) {
#pragma unroll
      for (int qp = 0; qp < 4; ++qp) stage_q(sn, t + 1, qp >> 1, qp & 1);
      asm volatile("s_waitcnt vmcnt(8)" ::: "memory");
    } else {
      asm volatile("s_waitcnt vmcnt(0)" ::: "memory");
    }
    __builtin_amdgcn_sched_barrier(0);
    __builtin_amdgcn_s_barrier();
    bf16x8 b0[4], b1[4];
#pragma unroll
    for (int j = 0; j < 4; ++j) {
      b0[j] = frag(sc, 1, brow + j * 16, 0);
      b1[j] = frag(sc, 1, brow + j * 16, 1);
    }
    __builtin_amdgcn_s_setprio(1);
#pragma unroll
    for (int im = 0; im < 8; ++im) {
      bf16x8 x0 = frag(sc, 0, arow + im * 16, 0);
      bf16x8 x1 = frag(sc, 0, arow + im * 16, 1);
#pragma unroll
      for (int j = 0; j < 4; ++j) {
        acc[im][j] = __builtin_amdgcn_mfma_f32_16x16x32_bf16(x0, b0[j], acc[im][j], 0, 0, 0);
        acc[im][j] = __builtin_amdgcn_mfma_f32_16x16x32_bf16(x1, b1[j], acc[im][j], 0, 0, 0);
      }
    }
    __builtin_amdgcn_s_setprio(0);
    __builtin_amdgcn_s_barrier();
  }

  const int crow0 = m0 + wr * 128 + fx * 4;
  const int ccol0 = n0 + wc * 64 + fr;
#pragma unroll
  for (int j = 0; j < 4; ++j) {
    const int col = ccol0 + j * 16;
    const float bv = bias[col];
#pragma unroll
    for (int im = 0; im < 8; ++im)
#pragma unroll
      for (int r = 0; r < 4; ++r)
        C[(long)(crow0 + im * 16 + r) * N + col] = (__bf16)(acc[im][j][r] + bv);
  }
}

// ---------------- GEMM: C = A @ B^T + bias (128-col tiles) ----------------
// EPI: 0 f32 store, 1 bf16 store,
//      6 gate1: msq *= f^2, magOut = sqrt(msq+eps) bf16
//      7 gate2: msq *= f^2
template <int EPI, int BM>
__global__ __launch_bounds__(256) void k_gemm_bt(
    const __bf16* __restrict__ A, const __bf16* __restrict__ B,
    const float* __restrict__ bias, void* __restrict__ Cout,
    int M, int N, int K, int Nreal,
    float* __restrict__ msq, __bf16* __restrict__ magOut) {
  constexpr int MR = BM / 32;
  __shared__ __align__(16) __bf16 As[2][BM * 32];
  __shared__ __align__(16) __bf16 Bs[2][128 * 32];
  const int tid = threadIdx.x;
  const int lane = tid & 63;
  const int wid = tid >> 6;
  const int wr = wid >> 1, wc = wid & 1;

  const int gx = gridDim.x, gy = gridDim.y;
  const int nwg = gx * gy;
  int bx, by;
  if ((nwg & 7) == 0) {
    const int lin = blockIdx.y * gx + blockIdx.x;
    const int cpx = nwg >> 3;
    const int w = (lin & 7) * cpx + (lin >> 3);
    bx = w / gy;
    by = w % gy;
  } else {
    bx = blockIdx.x;
    by = blockIdx.y;
  }
  const int m0 = by * BM;
  const int n0 = bx * 128;
  const int frow = lane & 15;
  const int fk = (lane >> 4) * 8;
  f32x4 acc[MR][4] = {};

  auto stage = [&](int buf, int k0) {
    const __bf16* Ab = A + (long)m0 * K + k0;
    const __bf16* Bb = B + (long)n0 * K + k0;
#pragma unroll
    for (int q = 0; q < BM / 64; ++q) {
      const int idx = q * 256 + tid;
      const int row = idx >> 2;
      const int col = (idx & 3) * 8;
      gld_lds16(Ab + (long)row * K + col, (char*)(&As[buf][0]) + idx * 16);
    }
#pragma unroll
    for (int q = 0; q < 2; ++q) {
      const int idx = q * 256 + tid;
      const int row = idx >> 2;
      const int col = (idx & 3) * 8;
      gld_lds16(Bb + (long)row * K + col, (char*)(&Bs[buf][0]) + idx * 16);
    }
  };

  const int nt = K >> 5;
  int cur = 0;
  stage(0, 0);
  __syncthreads();
  for (int t = 0; t < nt; ++t) {
    if (t + 1 < nt) stage(cur ^ 1, (t + 1) << 5);
    bf16x8 af[MR], bfr[4];
#pragma unroll
    for (int i = 0; i < MR; ++i)
      af[i] = *(const bf16x8*)(&As[cur][0] + (wr * (BM / 2) + i * 16 + frow) * 32 + fk);
#pragma unroll
    for (int i = 0; i < 4; ++i)
      bfr[i] = *(const bf16x8*)(&Bs[cur][0] + (wc * 64 + i * 16 + frow) * 32 + fk);
#pragma unroll
    for (int im = 0; im < MR; ++im)
#pragma unroll
      for (int in = 0; in < 4; ++in)
        acc[im][in] = __builtin_amdgcn_mfma_f32_16x16x32_bf16(af[im], bfr[in],
                                                              acc[im][in], 0, 0, 0);
    __syncthreads();
    cur ^= 1;
  }

  const int crow0 = m0 + wr * (BM / 2) + (lane >> 4) * 4;
  const int ccol0 = n0 + wc * 64 + (lane & 15);
#pragma unroll
  for (int in = 0; in < 4; ++in) {
    const int col = ccol0 + in * 16;
    if (col >= Nreal) continue;
    const float bv = bias[col];
#pragma unroll
    for (int im = 0; im < MR; ++im) {
#pragma unroll
      for (int r = 0; r < 4; ++r) {
        const long row = crow0 + im * 16 + r;
        const float v = acc[im][in][r] + bv;
        if (EPI == 0) {
          ((float*)Cout)[row * Nreal + col] = v;
        } else if (EPI == 1) {
          ((__bf16*)Cout)[row * Nreal + col] = (__bf16)v;
        } else {
          const float f = 1.f / (1.f + __expf(-v)) + 0.1f;
          const long ix = row * Nreal + col;
          const float m2 = msq[ix] * (f * f);
          msq[ix] = m2;
          if (EPI == 6) magOut[ix] = (__bf16)sqrtf(m2 + 1e-8f);
        }
      }
    }
  }
}

// ---------------- LN (over 1024) + gelu -> bf16 ----------------
__global__ __launch_bounds__(256) void k_ln_gelu(const float* __restrict__ y,
                                                 const float* __restrict__ g,
                                                 const float* __restrict__ b,
                                                 __bf16* __restrict__ h) {
  __shared__ float scr[8];
  const int tid = threadIdx.x;
  const long row = blockIdx.x;
  const float* yr = y + row * 1024;
  f32x4 v = *(const f32x4*)(yr + tid * 4);
  float ls = v[0] + v[1] + v[2] + v[3];
  const float mu = block_sum(ls, scr) * (1.f / 1024.f);
  float lss = 0.f;
#pragma unroll
  for (int j = 0; j < 4; ++j) {
    const float d = v[j] - mu;
    lss += d * d;
  }
  const float var = block_sum(lss, scr) * (1.f / 1024.f);
  const float rstd = rsqrtf(var + 1e-5f);
  bf16x4 o;
#pragma unroll
  for (int j = 0; j < 4; ++j) {
    const int c = tid * 4 + j;
    const float t = (v[j] - mu) * rstd * g[c] + b[c];
    o[j] = (__bf16)gelu_fast(t);
  }
  *(bf16x4*)(h + row * 1024 + tid * 4) = o;
}

// ---------------- stage C: outputs msq (f32) + mag0 (bf16) ----------------
__global__ __launch_bounds__(256) void k_stage_c(
    const __bf16* __restrict__ outb, const float* __restrict__ ln_g,
    const float* __restrict__ ln_b, const float* __restrict__ phases,
    const float* __restrict__ temp, float* __restrict__ msq,
    __bf16* __restrict__ mag0, int b0) {
  __shared__ float wrs[3][1024];
  __shared__ float wis[3][1024];
  __shared__ float gbuf[2048];
  __shared__ float scr[8];
  const int tid = threadIdx.x;
  const long b = blockIdx.x;

#pragma unroll 1
  for (int s = 0; s < 3; ++s) {
    const __bf16* src = outb + b * 6144 + s * 2048;
    bf16x8 v8 = *(const bf16x8*)(src + tid * 8);
    float x[8];
#pragma unroll
    for (int j = 0; j < 8; ++j) x[j] = (float)v8[j];
    float ls = 0.f;
#pragma unroll
    for (int j = 0; j < 8; ++j) ls += x[j];
    const float mu = block_sum(ls, scr) * (1.f / 2048.f);
    float lss = 0.f;
#pragma unroll
    for (int j = 0; j < 8; ++j) {
      const float d = x[j] - mu;
      lss += d * d;
    }
    const float var = block_sum(lss, scr) * (1.f / 2048.f);
    const float rstd = rsqrtf(var + 1e-5f);
    const float* lg = ln_g + s * 2048;
    const float* lb = ln_b + s * 2048;
    float nsq = 0.f;
#pragma unroll
    for (int j = 0; j < 8; ++j) {
      const int e = tid * 8 + j;
      const float yv = (x[j] - mu) * rstd * lg[e] + lb[e];
      const float gv = __expf(-yv * yv);
      gbuf[e] = gv;
      nsq += gv * gv;
    }
    const float normsq = block_sum(nsq, scr) + 1e-8f;
    const float factor = sqrtf(2.25f / normsq);
    const float ph = phases[s];
    const float cs = cosf(ph), sn = sinf(ph);
#pragma unroll
    for (int j = 0; j < 4; ++j) {
      const int h = j * 256 + tid;
      const float a = gbuf[h] * factor;
      const float bb = gbuf[h + 1024] * factor;
      wrs[s][h] = a * cs - bb * sn;
      wis[s][h] = a * sn + bb * cs;
    }
    __syncthreads();
  }

  float mr[4];
  float pmn = 0.f;
#pragma unroll
  for (int j = 0; j < 4; ++j) {
    const int h = j * 256 + tid;
    const float m = (wrs[0][h] + wrs[1][h] + wrs[2][h]) * (1.f / 3.f);
    mr[j] = m;
    pmn += m * m;
  }
  const float mnorm = sqrtf(block_sum(pmn, scr)) + 1e-8f;
  float csim[3];
#pragma unroll 1
  for (int s = 0; s < 3; ++s) {
    float pd = 0.f, pw = 0.f;
#pragma unroll
    for (int j = 0; j < 4; ++j) {
      const int h = j * 256 + tid;
      const float w = wrs[s][h];
      pd += w * mr[j];
      pw += w * w;
    }
    const float dot = block_sum(pd, scr);
    const float wn = sqrtf(block_sum(pw, scr)) + 1e-8f;
    csim[s] = dot / (wn * mnorm);
  }
  const float T = temp[0];
  const float t0 = csim[0] / T, t1 = csim[1] / T, t2 = csim[2] / T;
  const float mx = fmaxf(t0, fmaxf(t1, t2));
  const float e0 = __expf(t0 - mx), e1 = __expf(t1 - mx), e2 = __expf(t2 - mx);
  const float inv = 1.f / (e0 + e1 + e2);
  const float w0 = e0 * inv, w1 = e1 * inv, w2 = e2 * inv;
#pragma unroll
  for (int j = 0; j < 4; ++j) {
    const int h = j * 256 + tid;
    const float sr = wrs[0][h] * w0 + wrs[1][h] * w1 + wrs[2][h] * w2;
    const float si = wis[0][h] * w0 + wis[1][h] * w1 + wis[2][h] * w2;
    const float m2 = sr * sr + si * si;
    msq[(long)(b0 + b) * 1024 + h] = m2;
    mag0[(long)(b0 + b) * 1024 + h] = (__bf16)sqrtf(m2 + 1e-8f);
  }
}

// ---------------- fused top-8 (u64-key over msq) + sparse cls1 ----------------
__global__ __launch_bounds__(256) void k_topk_cls1(
    const float* __restrict__ msq,
    const float* __restrict__ w1t, const float* __restrict__ b1,
    __bf16* __restrict__ hid) {
  __shared__ u64 candk[32];
  __shared__ u64 selk_s[8];
  __shared__ float ssum_s;
  const int tid = threadIdx.x;
  const int lane = tid & 63;
  const int wv = tid >> 6;
  const long b = blockIdx.x;

  f32x4 mv = *(const f32x4*)(msq + b * 1024 + tid * 4);
  u64 key[4];
#pragma unroll
  for (int j = 0; j < 4; ++j)
    key[j] = ((u64)__float_as_uint(mv[j]) << 32) | (unsigned)(~(unsigned)(tid * 4 + j));
  u64 lm = key[0];
  int jm = 0;
#pragma unroll
  for (int j = 1; j < 4; ++j)
    if (key[j] > lm) { lm = key[j]; jm = j; }

#pragma unroll 1
  for (int it = 0; it < 8; ++it) {
    u64 bk = lm;
#pragma unroll
    for (int m = 1; m < 64; m <<= 1) {
      const u64 ok = __shfl_xor(bk, m, 64);
      bk = ok > bk ? ok : bk;
    }
    if (lane == 0) candk[wv * 8 + it] = bk;
    if (bk == lm) {
      key[jm] = 0ULL;
      lm = key[0]; jm = 0;
#pragma unroll
      for (int j = 1; j < 4; ++j)
        if (key[j] > lm) { lm = key[j]; jm = j; }
    }
  }
  __syncthreads();

  if (wv == 0) {
    u64 ck = (lane < 32) ? candk[lane] : 0ULL;
    float ss = 0.f;
#pragma unroll 1
    for (int it = 0; it < 8; ++it) {
      u64 bk = ck;
#pragma unroll
      for (int m = 1; m < 64; m <<= 1) {
        const u64 ok = __shfl_xor(bk, m, 64);
        bk = ok > bk ? ok : bk;
      }
      if (ck == bk) ck = 0ULL;
      if (lane == 0) {
        selk_s[it] = bk;
        ss += __uint_as_float((unsigned)(bk >> 32));
      }
    }
    if (lane == 0) ssum_s = ss;
  }
  __syncthreads();

  const float denom = 1.f / (ssum_s + 1e-8f);
  float p[8];
  int idx[8];
#pragma unroll
  for (int k = 0; k < 8; ++k) {
    const u64 kk = selk_s[k];
    p[k] = __uint_as_float((unsigned)(kk >> 32)) * denom;
    idx[k] = (int)(~(unsigned)kk & 1023u);
  }

  const int o0 = tid * 4;
  float acc0 = b1[o0], acc1 = b1[o0 + 1], acc2 = b1[o0 + 2], acc3 = b1[o0 + 3];
#pragma unroll
  for (int k = 0; k < 8; ++k) {
    const f32x4 wrow = *(const f32x4*)(w1t + (long)idx[k] * 1024 + o0);
    acc0 += p[k] * wrow[0];
    acc1 += p[k] * wrow[1];
    acc2 += p[k] * wrow[2];
    acc3 += p[k] * wrow[3];
  }
  bf16x4 o = {(__bf16)gelu_fast(acc0), (__bf16)gelu_fast(acc1),
              (__bf16)gelu_fast(acc2), (__bf16)gelu_fast(acc3)};
  *(bf16x4*)(hid + b * 1024 + o0) = o;
}

extern "C" void kernel_launch(void* const* d_in, const int* in_sizes, int n_in,
                              void* d_out, int out_size, void* d_ws, size_t ws_size,
                              hipStream_t stream) {
  const float* x      = (const float*)d_in[0];
  const float* proj_w = (const float*)d_in[1];
  const float* proj_b = (const float*)d_in[2];
  const float* ln_p_g = (const float*)d_in[3];
  const float* ln_p_b = (const float*)d_in[4];
  const float* wf_w   = (const float*)d_in[5];
  const float* wf_b   = (const float*)d_in[6];
  const float* ln_g   = (const float*)d_in[7];
  const float* ln_b   = (const float*)d_in[8];
  const float* temperature = (const float*)d_in[9];
  const float* phases = (const float*)d_in[10];
  const float* gate_w = (const float*)d_in[11];
  const float* gate_b = (const float*)d_in[12];
  const float* cls_w1 = (const float*)d_in[13];
  const float* cls_b1 = (const float*)d_in[14];
  const float* cls_w2 = (const float*)d_in[15];
  const float* cls_b2 = (const float*)d_in[16];
  float* out = (float*)d_out;
  (void)in_sizes; (void)n_in; (void)out_size;

  char* ws = (char*)d_ws;
  const size_t MB = 1024 * 1024;

  if (ws_size >= 196 * MB) {
    // ---- full layout (196MB) ----
    //  [0,32):  xb (casts,G1) -> msq (stage_c..topk)
    //  [32,64): y1 (G1,ln) -> mag0@32, mag1@48
    //  [64,160): outb (dead after stage_c) -> hid@64, w1t@96
    //  [160,176): hb    [176,188): wfwb
    //  [188,190): gwb   [190,192): c2b   [192,196): w1b
    __bf16* xb   = (__bf16*)(ws + 0);
    float*  msq  = (float*)(ws + 0);
    float*  y1   = (float*)(ws + 32 * MB);
    __bf16* mag0 = (__bf16*)(ws + 32 * MB);
    __bf16* mag1 = (__bf16*)(ws + 48 * MB);
    __bf16* outb = (__bf16*)(ws + 64 * MB);
    __bf16* hid  = (__bf16*)(ws + 64 * MB);
    float*  w1t  = (float*)(ws + 96 * MB);
    __bf16* hb   = (__bf16*)(ws + 160 * MB);
    __bf16* wfwb = (__bf16*)(ws + 176 * MB);
    __bf16* gwb  = (__bf16*)(ws + 188 * MB);
    __bf16* c2b  = (__bf16*)(ws + 190 * MB);
    __bf16* w1b  = (__bf16*)(ws + 192 * MB);

    k_cast_bf16<<<16384, 256, 0, stream>>>(x, xb);
    k_cast_weights<<<9216, 256, 0, stream>>>(proj_w, w1b, wf_w, wfwb, gate_w, gwb);
    k_cast_pad<<<1024, 256, 0, stream>>>(cls_w2, c2b, 1000, 1024);

    k_gemm_bt<0, 64><<<dim3(8, 128), 256, 0, stream>>>(xb, w1b, proj_b, y1, 8192, 1024, 2048, 1024, nullptr, nullptr);
    k_ln_gelu<<<8192, 256, 0, stream>>>(y1, ln_p_g, ln_p_b, hb);

    k_gemm256_bt<<<dim3(24, 32), 512, 0, stream>>>(hb, wfwb, wf_b, outb, 8192, 6144, 1024);
    k_stage_c<<<8192, 256, 0, stream>>>(outb, ln_g, ln_b, phases, temperature, msq, mag0, 0);

    k_transpose1k<<<dim3(32, 32), 256, 0, stream>>>(cls_w1, w1t);
    // self-mod: gate1 (msq *= f^2, mag1 out), gate2 (msq *= f^2)
    k_gemm_bt<6, 64><<<dim3(8, 128), 256, 0, stream>>>(mag0, gwb, gate_b, nullptr, 8192, 1024, 1024, 1024, msq, mag1);
    k_gemm_bt<7, 64><<<dim3(8, 128), 256, 0, stream>>>(mag1, gwb, gate_b, nullptr, 8192, 1024, 1024, 1024, msq, nullptr);

    k_topk_cls1<<<8192, 256, 0, stream>>>(msq, w1t, cls_b1, hid);
    k_gemm_bt<0, 64><<<dim3(8, 128), 256, 0, stream>>>(hid, c2b, cls_b2, out, 8192, 1024, 1024, 1000, nullptr, nullptr);
  } else {
    // ---- fallback layout (128MB): 4-chunk G2 path ----
    //  [0,32):  xb -> msq      [32,64): y1 / outc(24MB) -> mag1@32, hid@48
    //  [64,68): w1b -> mag0@[64,80)
    //  [96,108): wfwb   [108,124): hb -> w1t@[108,112)
    //  [124,126): gwb   [126,128): c2b
    __bf16* xb   = (__bf16*)(ws + 0);
    float*  msq  = (float*)(ws + 0);
    float*  y1   = (float*)(ws + 32 * MB);
    __bf16* outc = (__bf16*)(ws + 32 * MB);
    __bf16* mag1 = (__bf16*)(ws + 32 * MB);
    __bf16* hid  = (__bf16*)(ws + 48 * MB);
    __bf16* w1b  = (__bf16*)(ws + 64 * MB);
    __bf16* mag0 = (__bf16*)(ws + 64 * MB);
    __bf16* wfwb = (__bf16*)(ws + 96 * MB);
    __bf16* hb   = (__bf16*)(ws + 108 * MB);
    float*  w1t  = (float*)(ws + 108 * MB);
    __bf16* gwb  = (__bf16*)(ws + 124 * MB);
    __bf16* c2b  = (__bf16*)(ws + 126 * MB);

    k_cast_bf16<<<16384, 256, 0, stream>>>(x, xb);
    k_cast_weights<<<9216, 256, 0, stream>>>(proj_w, w1b, wf_w, wfwb, gate_w, gwb);
    k_cast_pad<<<1024, 256, 0, stream>>>(cls_w2, c2b, 1000, 1024);

    k_gemm_bt<0, 64><<<dim3(8, 128), 256, 0, stream>>>(xb, w1b, proj_b, y1, 8192, 1024, 2048, 1024, nullptr, nullptr);
    k_ln_gelu<<<8192, 256, 0, stream>>>(y1, ln_p_g, ln_p_b, hb);

    for (int c = 0; c < 4; ++c) {
      k_gemm_bt<1, 128><<<dim3(48, 16), 256, 0, stream>>>(hb + (size_t)c * 2048 * 1024, wfwb, wf_b,
                                                          outc, 2048, 6144, 1024, 6144, nullptr, nullptr);
      k_stage_c<<<2048, 256, 0, stream>>>(outc, ln_g, ln_b, phases, temperature,
                                          msq, mag0, c * 2048);
    }

    k_transpose1k<<<dim3(32, 32), 256, 0, stream>>>(cls_w1, w1t);
    k_gemm_bt<6, 64><<<dim3(8, 128), 256, 0, stream>>>(mag0, gwb, gate_b, nullptr, 8192, 1024, 1024, 1024, msq, mag1);
    k_gemm_bt<7, 64><<<dim3(8, 128), 256, 0, stream>>>(mag1, gwb, gate_b, nullptr, 8192, 1024, 1024, 1024, msq, nullptr);

    k_topk_cls1<<<8192, 256, 0, stream>>>(msq, w1t, cls_b1, hid);
    k_gemm_bt<0, 64><<<dim3(8, 128), 256, 0, stream>>>(hid, c2b, cls_b2, out, 8192, 1024, 1024, 1000, nullptr, nullptr);
  }
}

// Round 11
// 500.817 us; speedup vs baseline: 1.1245x; 1.0078x over previous
//
#include <hip/hip_runtime.h>
#include <cstdint>

typedef __attribute__((ext_vector_type(8))) __bf16 bf16x8;
typedef __attribute__((ext_vector_type(4))) __bf16 bf16x4;
typedef __attribute__((ext_vector_type(4))) float f32x4;
typedef unsigned long long u64;

__device__ __forceinline__ void gld_lds16(const void* g, void* l) {
  __builtin_amdgcn_global_load_lds(
      (const __attribute__((address_space(1))) void*)g,
      (__attribute__((address_space(3))) void*)l, 16, 0, 0);
}

__device__ __forceinline__ float block_sum(float v, float* scr) {
#pragma unroll
  for (int off = 32; off > 0; off >>= 1) v += __shfl_down(v, off, 64);
  const int w = threadIdx.x >> 6;
  __syncthreads();
  if ((threadIdx.x & 63) == 0) scr[w] = v;
  __syncthreads();
  float s = 0.f;
  const int nw = blockDim.x >> 6;
  for (int i = 0; i < nw; ++i) s += scr[i];
  return s;
}

// fast gelu: A&S 7.1.26 erf (|err|<1.5e-7) + hw exp
__device__ __forceinline__ float gelu_fast(float x) {
  const float ax = fabsf(x) * 0.70710678118654752f;
  const float t = 1.f / (1.f + 0.3275911f * ax);
  const float e = __expf(-ax * ax);
  float poly = 1.061405429f;
  poly = poly * t - 1.453152027f;
  poly = poly * t + 1.421413741f;
  poly = poly * t - 0.284496736f;
  poly = poly * t + 0.254829592f;
  const float erfax = 1.f - poly * t * e;
  const float er = copysignf(erfax, x);
  return 0.5f * x * (1.f + er);
}

// ---------------- casts ----------------
__global__ __launch_bounds__(256) void k_cast_bf16(const float* __restrict__ in,
                                                   __bf16* __restrict__ out) {
  const long i = ((long)blockIdx.x * 256 + threadIdx.x) * 4;
  f32x4 v = *(const f32x4*)(in + i);
  bf16x4 o = {(__bf16)v[0], (__bf16)v[1], (__bf16)v[2], (__bf16)v[3]};
  *(bf16x4*)(out + i) = o;
}

// combined weight casts: proj_w(2048 blk) | wf_w(6144 blk) | gate_w(1024 blk)
__global__ __launch_bounds__(256) void k_cast_weights(
    const float* __restrict__ pw, __bf16* __restrict__ w1b,
    const float* __restrict__ wfw, __bf16* __restrict__ wfwb,
    const float* __restrict__ gw, __bf16* __restrict__ gwb) {
  const int bid = blockIdx.x;
  const float* in;
  __bf16* out;
  long base;
  if (bid < 2048) { in = pw; out = w1b; base = (long)bid * 1024; }
  else if (bid < 8192) { in = wfw; out = wfwb; base = (long)(bid - 2048) * 1024; }
  else { in = gw; out = gwb; base = (long)(bid - 8192) * 1024; }
  const long i = base + threadIdx.x * 4;
  f32x4 v = *(const f32x4*)(in + i);
  bf16x4 o = {(__bf16)v[0], (__bf16)v[1], (__bf16)v[2], (__bf16)v[3]};
  *(bf16x4*)(out + i) = o;
}

__global__ __launch_bounds__(256) void k_cast_pad(const float* __restrict__ in,
                                                  __bf16* __restrict__ out,
                                                  int rows_real, int cols) {
  const long i = ((long)blockIdx.x * 256 + threadIdx.x) * 4;
  const int row = (int)(i / cols);
  const int col = (int)(i % cols);
  bf16x4 o;
  if (row < rows_real) {
    f32x4 v = *(const f32x4*)(in + (long)row * cols + col);
    o = (bf16x4){(__bf16)v[0], (__bf16)v[1], (__bf16)v[2], (__bf16)v[3]};
  } else {
    o = (bf16x4){(__bf16)0.f, (__bf16)0.f, (__bf16)0.f, (__bf16)0.f};
  }
  *(bf16x4*)(out + i) = o;
}

// ---------------- transpose 1024x1024 f32 ----------------
__global__ __launch_bounds__(256) void k_transpose1k(const float* __restrict__ in,
                                                     float* __restrict__ out) {
  __shared__ float t[32][33];
  const int tx = threadIdx.x & 31;
  const int ty = threadIdx.x >> 5;
  const int r0 = blockIdx.y * 32, c0 = blockIdx.x * 32;
#pragma unroll
  for (int k = 0; k < 4; ++k)
    t[ty + 8 * k][tx] = in[(long)(r0 + ty + 8 * k) * 1024 + c0 + tx];
  __syncthreads();
#pragma unroll
  for (int k = 0; k < 4; ++k)
    out[(long)(c0 + ty + 8 * k) * 1024 + r0 + tx] = t[tx][ty + 8 * k];
}

// ============ 256x256 8-wave BK=64 GEMM + LDS-bounce full-line epilogue ============
__global__ __launch_bounds__(512, 1) void k_gemm256_bt(
    const __bf16* __restrict__ A, const __bf16* __restrict__ B,
    const float* __restrict__ bias, __bf16* __restrict__ C,
    int M, int N, int K) {
  __shared__ __align__(16) __bf16 lds[2][2][256 * 64];  // [slot][mat][row*64+k]
  const int tid = threadIdx.x;
  const int lane = tid & 63;
  const int wid = tid >> 6;
  const int wr = wid >> 2;
  const int wc = wid & 3;
  const int gx = gridDim.x, gy = gridDim.y;
  const int nwg = gx * gy;
  const int lin = blockIdx.y * gx + blockIdx.x;
  const int cpx = nwg >> 3;
  const int wsw = (lin & 7) * cpx + (lin >> 3);
  const int bx = wsw / gy, by = wsw % gy;
  const int m0 = by * 256, n0 = bx * 256;
  const int fr = lane & 15;
  const int fx = lane >> 4;
  const int px = lane & 7;

  const __bf16* Abase = A + (long)m0 * K;
  const __bf16* Bbase = B + (long)n0 * K;

  auto stage_q = [&](int slot, int kt, int mat, int half) {
    const __bf16* src = (mat ? Bbase : Abase) + kt * 64;
#pragma unroll
    for (int q = 0; q < 2; ++q) {
      const int idx = q * 512 + tid;
      const int r = idx >> 3;
      const int pblk = idx & 7;
      const int row = half * 128 + r;
      const int lblk = pblk ^ (r & 7);
      gld_lds16(src + (long)row * K + lblk * 8,
                (char*)&lds[slot][mat][row * 64 + pblk * 8]);
    }
  };
  auto frag = [&](int slot, int mat, int row, int ks) -> bf16x8 {
    return *(const bf16x8*)&lds[slot][mat][row * 64 + ((((ks << 2) + fx) ^ px) << 3)];
  };

  f32x4 acc[8][4] = {};
  const int nt = K >> 6;
#pragma unroll
  for (int qp = 0; qp < 4; ++qp) stage_q(0, 0, qp >> 1, qp & 1);

  const int arow = wr * 128 + fr;
  const int brow = wc * 64 + fr;

  for (int t = 0; t < nt; ++t) {
    const int sc = t & 1, sn = sc ^ 1;
    if (t + 1 < nt) {
#pragma unroll
      for (int qp = 0; qp < 4; ++qp) stage_q(sn, t + 1, qp >> 1, qp & 1);
      asm volatile("s_waitcnt vmcnt(8)" ::: "memory");
    } else {
      asm volatile("s_waitcnt vmcnt(0)" ::: "memory");
    }
    __builtin_amdgcn_sched_barrier(0);
    __builtin_amdgcn_s_barrier();
    bf16x8 b0[4], b1[4];
#pragma unroll
    for (int j = 0; j < 4; ++j) {
      b0[j] = frag(sc, 1, brow + j * 16, 0);
      b1[j] = frag(sc, 1, brow + j * 16, 1);
    }
    __builtin_amdgcn_s_setprio(1);
#pragma unroll
    for (int im = 0; im < 8; ++im) {
      bf16x8 x0 = frag(sc, 0, arow + im * 16, 0);
      bf16x8 x1 = frag(sc, 0, arow + im * 16, 1);
#pragma unroll
      for (int j = 0; j < 4; ++j) {
        acc[im][j] = __builtin_amdgcn_mfma_f32_16x16x32_bf16(x0, b0[j], acc[im][j], 0, 0, 0);
        acc[im][j] = __builtin_amdgcn_mfma_f32_16x16x32_bf16(x1, b1[j], acc[im][j], 0, 0, 0);
      }
    }
    __builtin_amdgcn_s_setprio(0);
    __builtin_amdgcn_s_barrier();
  }

  // ---- epilogue: bounce C tile through dead staging LDS (exactly 256x256 bf16) ----
  __bf16* cb = (__bf16*)&lds[0][0][0];
  const int lm0 = wr * 128 + fx * 4;
  const int lc0 = wc * 64 + fr;
#pragma unroll
  for (int j = 0; j < 4; ++j) {
    const float bv = bias[n0 + lc0 + j * 16];
#pragma unroll
    for (int im = 0; im < 8; ++im)
#pragma unroll
      for (int r = 0; r < 4; ++r)
        cb[(lm0 + im * 16 + r) * 256 + lc0 + j * 16] = (__bf16)(acc[im][j][r] + bv);
  }
  __syncthreads();
#pragma unroll
  for (int q = 0; q < 16; ++q) {
    const int idx = q * 512 + tid;   // 8192 chunks of 16B
    const int row = idx >> 5;        // 32 chunks per 512B row
    const int c8 = (idx & 31) * 8;   // bf16 col
    *(f32x4*)(C + (long)(m0 + row) * N + n0 + c8) = *(const f32x4*)(cb + row * 256 + c8);
  }
}

// ---------------- GEMM: C = A @ B^T + bias (128-col tiles) ----------------
// EPI: 0 f32 store (LDS-bounce full-line), 1 bf16 store (scatter; fallback only),
//      6 gate1: msq *= f^2, magOut = sqrt(msq+eps) bf16
//      7 gate2: msq *= f^2
template <int EPI, int BM>
__global__ __launch_bounds__(256) void k_gemm_bt(
    const __bf16* __restrict__ A, const __bf16* __restrict__ B,
    const float* __restrict__ bias, void* __restrict__ Cout,
    int M, int N, int K, int Nreal,
    float* __restrict__ msq, __bf16* __restrict__ magOut) {
  constexpr int MR = BM / 32;
  constexpr int STAGE_B = (2 * BM * 32 + 2 * 128 * 32) * 2;
  constexpr int CB_B = BM * 64 * 4;
  constexpr int SMEM_B = STAGE_B > CB_B ? STAGE_B : CB_B;
  __shared__ __align__(16) char smem[SMEM_B];
  __bf16* As = (__bf16*)smem;                          // [2][BM*32]
  __bf16* Bs = (__bf16*)(smem + (size_t)2 * BM * 32 * 2);  // [2][128*32]
  float* cb = (float*)smem;                            // bounce region (BM x 64 f32)
  const int tid = threadIdx.x;
  const int lane = tid & 63;
  const int wid = tid >> 6;
  const int wr = wid >> 1, wc = wid & 1;

  const int gx = gridDim.x, gy = gridDim.y;
  const int nwg = gx * gy;
  int bx, by;
  if ((nwg & 7) == 0) {
    const int lin = blockIdx.y * gx + blockIdx.x;
    const int cpx = nwg >> 3;
    const int w = (lin & 7) * cpx + (lin >> 3);
    bx = w / gy;
    by = w % gy;
  } else {
    bx = blockIdx.x;
    by = blockIdx.y;
  }
  const int m0 = by * BM;
  const int n0 = bx * 128;
  const int frow = lane & 15;
  const int fk = (lane >> 4) * 8;
  f32x4 acc[MR][4] = {};

  auto stage = [&](int buf, int k0) {
    const __bf16* Ab = A + (long)m0 * K + k0;
    const __bf16* Bb = B + (long)n0 * K + k0;
    __bf16* Asb = As + buf * BM * 32;
    __bf16* Bsb = Bs + buf * 128 * 32;
#pragma unroll
    for (int q = 0; q < BM / 64; ++q) {
      const int idx = q * 256 + tid;
      const int row = idx >> 2;
      const int col = (idx & 3) * 8;
      gld_lds16(Ab + (long)row * K + col, (char*)Asb + idx * 16);
    }
#pragma unroll
    for (int q = 0; q < 2; ++q) {
      const int idx = q * 256 + tid;
      const int row = idx >> 2;
      const int col = (idx & 3) * 8;
      gld_lds16(Bb + (long)row * K + col, (char*)Bsb + idx * 16);
    }
  };

  const int nt = K >> 5;
  int cur = 0;
  stage(0, 0);
  __syncthreads();
  for (int t = 0; t < nt; ++t) {
    if (t + 1 < nt) stage(cur ^ 1, (t + 1) << 5);
    bf16x8 af[MR], bfr[4];
#pragma unroll
    for (int i = 0; i < MR; ++i)
      af[i] = *(const bf16x8*)(As + cur * BM * 32 + (wr * (BM / 2) + i * 16 + frow) * 32 + fk);
#pragma unroll
    for (int i = 0; i < 4; ++i)
      bfr[i] = *(const bf16x8*)(Bs + cur * 128 * 32 + (wc * 64 + i * 16 + frow) * 32 + fk);
#pragma unroll
    for (int im = 0; im < MR; ++im)
#pragma unroll
      for (int in = 0; in < 4; ++in)
        acc[im][in] = __builtin_amdgcn_mfma_f32_16x16x32_bf16(af[im], bfr[in],
                                                              acc[im][in], 0, 0, 0);
    __syncthreads();
    cur ^= 1;
  }

  if (EPI == 0) {
    // bounce via LDS in two 64-col halves -> full-line f32x4 streaming stores
#pragma unroll 1
    for (int h = 0; h < 2; ++h) {
      __syncthreads();
      if (wc == h) {
#pragma unroll
        for (int in = 0; in < 4; ++in) {
          const int col = n0 + h * 64 + in * 16 + frow;
          const float bv = (col < Nreal) ? bias[col] : 0.f;
          const int lcc = in * 16 + frow;
#pragma unroll
          for (int im = 0; im < MR; ++im)
#pragma unroll
            for (int r = 0; r < 4; ++r)
              cb[(wr * (BM / 2) + (lane >> 4) * 4 + im * 16 + r) * 64 + lcc] =
                  acc[im][in][r] + bv;
        }
      }
      __syncthreads();
#pragma unroll
      for (int q = 0; q < BM / 16; ++q) {
        const int idx = q * 256 + tid;  // BM*16 chunks of 16B
        const int row = idx >> 4;       // 16 chunks per 256B row
        const int c4 = (idx & 15) * 4;  // f32 col
        const int gc = n0 + h * 64 + c4;
        if (gc < Nreal)
          *(f32x4*)((float*)Cout + (long)(m0 + row) * Nreal + gc) =
              *(const f32x4*)(cb + row * 64 + c4);
      }
    }
  } else {
    const int crow0 = m0 + wr * (BM / 2) + (lane >> 4) * 4;
    const int ccol0 = n0 + wc * 64 + (lane & 15);
#pragma unroll
    for (int in = 0; in < 4; ++in) {
      const int col = ccol0 + in * 16;
      if (col >= Nreal) continue;
      const float bv = bias[col];
#pragma unroll
      for (int im = 0; im < MR; ++im) {
#pragma unroll
        for (int r = 0; r < 4; ++r) {
          const long row = crow0 + im * 16 + r;
          const float v = acc[im][in][r] + bv;
          if (EPI == 1) {
            ((__bf16*)Cout)[row * Nreal + col] = (__bf16)v;
          } else {
            const float f = 1.f / (1.f + __expf(-v)) + 0.1f;
            const long ix = row * Nreal + col;
            const float m2 = msq[ix] * (f * f);
            msq[ix] = m2;
            if (EPI == 6) magOut[ix] = (__bf16)sqrtf(m2 + 1e-8f);
          }
        }
      }
    }
  }
}

// ---------------- LN (over 1024) + gelu -> bf16 ----------------
__global__ __launch_bounds__(256) void k_ln_gelu(const float* __restrict__ y,
                                                 const float* __restrict__ g,
                                                 const float* __restrict__ b,
                                                 __bf16* __restrict__ h) {
  __shared__ float scr[8];
  const int tid = threadIdx.x;
  const long row = blockIdx.x;
  const float* yr = y + row * 1024;
  f32x4 v = *(const f32x4*)(yr + tid * 4);
  float ls = v[0] + v[1] + v[2] + v[3];
  const float mu = block_sum(ls, scr) * (1.f / 1024.f);
  float lss = 0.f;
#pragma unroll
  for (int j = 0; j < 4; ++j) {
    const float d = v[j] - mu;
    lss += d * d;
  }
  const float var = block_sum(lss, scr) * (1.f / 1024.f);
  const float rstd = rsqrtf(var + 1e-5f);
  bf16x4 o;
#pragma unroll
  for (int j = 0; j < 4; ++j) {
    const int c = tid * 4 + j;
    const float t = (v[j] - mu) * rstd * g[c] + b[c];
    o[j] = (__bf16)gelu_fast(t);
  }
  *(bf16x4*)(h + row * 1024 + tid * 4) = o;
}

// ---------------- stage C: outputs msq (f32) + mag0 (bf16) ----------------
__global__ __launch_bounds__(256) void k_stage_c(
    const __bf16* __restrict__ outb, const float* __restrict__ ln_g,
    const float* __restrict__ ln_b, const float* __restrict__ phases,
    const float* __restrict__ temp, float* __restrict__ msq,
    __bf16* __restrict__ mag0, int b0) {
  __shared__ float wrs[3][1024];
  __shared__ float wis[3][1024];
  __shared__ float gbuf[2048];
  __shared__ float scr[8];
  const int tid = threadIdx.x;
  const long b = blockIdx.x;

#pragma unroll 1
  for (int s = 0; s < 3; ++s) {
    const __bf16* src = outb + b * 6144 + s * 2048;
    bf16x8 v8 = *(const bf16x8*)(src + tid * 8);
    float x[8];
#pragma unroll
    for (int j = 0; j < 8; ++j) x[j] = (float)v8[j];
    float ls = 0.f;
#pragma unroll
    for (int j = 0; j < 8; ++j) ls += x[j];
    const float mu = block_sum(ls, scr) * (1.f / 2048.f);
    float lss = 0.f;
#pragma unroll
    for (int j = 0; j < 8; ++j) {
      const float d = x[j] - mu;
      lss += d * d;
    }
    const float var = block_sum(lss, scr) * (1.f / 2048.f);
    const float rstd = rsqrtf(var + 1e-5f);
    const float* lg = ln_g + s * 2048;
    const float* lb = ln_b + s * 2048;
    float nsq = 0.f;
#pragma unroll
    for (int j = 0; j < 8; ++j) {
      const int e = tid * 8 + j;
      const float yv = (x[j] - mu) * rstd * lg[e] + lb[e];
      const float gv = __expf(-yv * yv);
      gbuf[e] = gv;
      nsq += gv * gv;
    }
    const float normsq = block_sum(nsq, scr) + 1e-8f;
    const float factor = sqrtf(2.25f / normsq);
    const float ph = phases[s];
    const float cs = cosf(ph), sn = sinf(ph);
#pragma unroll
    for (int j = 0; j < 4; ++j) {
      const int h = j * 256 + tid;
      const float a = gbuf[h] * factor;
      const float bb = gbuf[h + 1024] * factor;
      wrs[s][h] = a * cs - bb * sn;
      wis[s][h] = a * sn + bb * cs;
    }
    __syncthreads();
  }

  float mr[4];
  float pmn = 0.f;
#pragma unroll
  for (int j = 0; j < 4; ++j) {
    const int h = j * 256 + tid;
    const float m = (wrs[0][h] + wrs[1][h] + wrs[2][h]) * (1.f / 3.f);
    mr[j] = m;
    pmn += m * m;
  }
  const float mnorm = sqrtf(block_sum(pmn, scr)) + 1e-8f;
  float csim[3];
#pragma unroll 1
  for (int s = 0; s < 3; ++s) {
    float pd = 0.f, pw = 0.f;
#pragma unroll
    for (int j = 0; j < 4; ++j) {
      const int h = j * 256 + tid;
      const float w = wrs[s][h];
      pd += w * mr[j];
      pw += w * w;
    }
    const float dot = block_sum(pd, scr);
    const float wn = sqrtf(block_sum(pw, scr)) + 1e-8f;
    csim[s] = dot / (wn * mnorm);
  }
  const float T = temp[0];
  const float t0 = csim[0] / T, t1 = csim[1] / T, t2 = csim[2] / T;
  const float mx = fmaxf(t0, fmaxf(t1, t2));
  const float e0 = __expf(t0 - mx), e1 = __expf(t1 - mx), e2 = __expf(t2 - mx);
  const float inv = 1.f / (e0 + e1 + e2);
  const float w0 = e0 * inv, w1 = e1 * inv, w2 = e2 * inv;
#pragma unroll
  for (int j = 0; j < 4; ++j) {
    const int h = j * 256 + tid;
    const float sr = wrs[0][h] * w0 + wrs[1][h] * w1 + wrs[2][h] * w2;
    const float si = wis[0][h] * w0 + wis[1][h] * w1 + wis[2][h] * w2;
    const float m2 = sr * sr + si * si;
    msq[(long)(b0 + b) * 1024 + h] = m2;
    mag0[(long)(b0 + b) * 1024 + h] = (__bf16)sqrtf(m2 + 1e-8f);
  }
}

// ---------------- fused top-8 (u64-key over msq) + sparse cls1 ----------------
__global__ __launch_bounds__(256) void k_topk_cls1(
    const float* __restrict__ msq,
    const float* __restrict__ w1t, const float* __restrict__ b1,
    __bf16* __restrict__ hid) {
  __shared__ u64 candk[32];
  __shared__ u64 selk_s[8];
  __shared__ float ssum_s;
  const int tid = threadIdx.x;
  const int lane = tid & 63;
  const int wv = tid >> 6;
  const long b = blockIdx.x;

  f32x4 mv = *(const f32x4*)(msq + b * 1024 + tid * 4);
  u64 key[4];
#pragma unroll
  for (int j = 0; j < 4; ++j)
    key[j] = ((u64)__float_as_uint(mv[j]) << 32) | (unsigned)(~(unsigned)(tid * 4 + j));
  u64 lm = key[0];
  int jm = 0;
#pragma unroll
  for (int j = 1; j < 4; ++j)
    if (key[j] > lm) { lm = key[j]; jm = j; }

#pragma unroll 1
  for (int it = 0; it < 8; ++it) {
    u64 bk = lm;
#pragma unroll
    for (int m = 1; m < 64; m <<= 1) {
      const u64 ok = __shfl_xor(bk, m, 64);
      bk = ok > bk ? ok : bk;
    }
    if (lane == 0) candk[wv * 8 + it] = bk;
    if (bk == lm) {
      key[jm] = 0ULL;
      lm = key[0]; jm = 0;
#pragma unroll
      for (int j = 1; j < 4; ++j)
        if (key[j] > lm) { lm = key[j]; jm = j; }
    }
  }
  __syncthreads();

  if (wv == 0) {
    u64 ck = (lane < 32) ? candk[lane] : 0ULL;
    float ss = 0.f;
#pragma unroll 1
    for (int it = 0; it < 8; ++it) {
      u64 bk = ck;
#pragma unroll
      for (int m = 1; m < 64; m <<= 1) {
        const u64 ok = __shfl_xor(bk, m, 64);
        bk = ok > bk ? ok : bk;
      }
      if (ck == bk) ck = 0ULL;
      if (lane == 0) {
        selk_s[it] = bk;
        ss += __uint_as_float((unsigned)(bk >> 32));
      }
    }
    if (lane == 0) ssum_s = ss;
  }
  __syncthreads();

  const float denom = 1.f / (ssum_s + 1e-8f);
  float p[8];
  int idx[8];
#pragma unroll
  for (int k = 0; k < 8; ++k) {
    const u64 kk = selk_s[k];
    p[k] = __uint_as_float((unsigned)(kk >> 32)) * denom;
    idx[k] = (int)(~(unsigned)kk & 1023u);
  }

  const int o0 = tid * 4;
  float acc0 = b1[o0], acc1 = b1[o0 + 1], acc2 = b1[o0 + 2], acc3 = b1[o0 + 3];
#pragma unroll
  for (int k = 0; k < 8; ++k) {
    const f32x4 wrow = *(const f32x4*)(w1t + (long)idx[k] * 1024 + o0);
    acc0 += p[k] * wrow[0];
    acc1 += p[k] * wrow[1];
    acc2 += p[k] * wrow[2];
    acc3 += p[k] * wrow[3];
  }
  bf16x4 o = {(__bf16)gelu_fast(acc0), (__bf16)gelu_fast(acc1),
              (__bf16)gelu_fast(acc2), (__bf16)gelu_fast(acc3)};
  *(bf16x4*)(hid + b * 1024 + o0) = o;
}

extern "C" void kernel_launch(void* const* d_in, const int* in_sizes, int n_in,
                              void* d_out, int out_size, void* d_ws, size_t ws_size,
                              hipStream_t stream) {
  const float* x      = (const float*)d_in[0];
  const float* proj_w = (const float*)d_in[1];
  const float* proj_b = (const float*)d_in[2];
  const float* ln_p_g = (const float*)d_in[3];
  const float* ln_p_b = (const float*)d_in[4];
  const float* wf_w   = (const float*)d_in[5];
  const float* wf_b   = (const float*)d_in[6];
  const float* ln_g   = (const float*)d_in[7];
  const float* ln_b   = (const float*)d_in[8];
  const float* temperature = (const float*)d_in[9];
  const float* phases = (const float*)d_in[10];
  const float* gate_w = (const float*)d_in[11];
  const float* gate_b = (const float*)d_in[12];
  const float* cls_w1 = (const float*)d_in[13];
  const float* cls_b1 = (const float*)d_in[14];
  const float* cls_w2 = (const float*)d_in[15];
  const float* cls_b2 = (const float*)d_in[16];
  float* out = (float*)d_out;
  (void)in_sizes; (void)n_in; (void)out_size;

  char* ws = (char*)d_ws;
  const size_t MB = 1024 * 1024;

  if (ws_size >= 196 * MB) {
    // ---- full layout (196MB) ----
    __bf16* xb   = (__bf16*)(ws + 0);
    float*  msq  = (float*)(ws + 0);
    float*  y1   = (float*)(ws + 32 * MB);
    __bf16* mag0 = (__bf16*)(ws + 32 * MB);
    __bf16* mag1 = (__bf16*)(ws + 48 * MB);
    __bf16* outb = (__bf16*)(ws + 64 * MB);
    __bf16* hid  = (__bf16*)(ws + 64 * MB);
    float*  w1t  = (float*)(ws + 96 * MB);
    __bf16* hb   = (__bf16*)(ws + 160 * MB);
    __bf16* wfwb = (__bf16*)(ws + 176 * MB);
    __bf16* gwb  = (__bf16*)(ws + 188 * MB);
    __bf16* c2b  = (__bf16*)(ws + 190 * MB);
    __bf16* w1b  = (__bf16*)(ws + 192 * MB);

    k_cast_bf16<<<16384, 256, 0, stream>>>(x, xb);
    k_cast_weights<<<9216, 256, 0, stream>>>(proj_w, w1b, wf_w, wfwb, gate_w, gwb);
    k_cast_pad<<<1024, 256, 0, stream>>>(cls_w2, c2b, 1000, 1024);

    k_gemm_bt<0, 64><<<dim3(8, 128), 256, 0, stream>>>(xb, w1b, proj_b, y1, 8192, 1024, 2048, 1024, nullptr, nullptr);
    k_ln_gelu<<<8192, 256, 0, stream>>>(y1, ln_p_g, ln_p_b, hb);

    k_gemm256_bt<<<dim3(24, 32), 512, 0, stream>>>(hb, wfwb, wf_b, outb, 8192, 6144, 1024);
    k_stage_c<<<8192, 256, 0, stream>>>(outb, ln_g, ln_b, phases, temperature, msq, mag0, 0);

    k_transpose1k<<<dim3(32, 32), 256, 0, stream>>>(cls_w1, w1t);
    k_gemm_bt<6, 64><<<dim3(8, 128), 256, 0, stream>>>(mag0, gwb, gate_b, nullptr, 8192, 1024, 1024, 1024, msq, mag1);
    k_gemm_bt<7, 64><<<dim3(8, 128), 256, 0, stream>>>(mag1, gwb, gate_b, nullptr, 8192, 1024, 1024, 1024, msq, nullptr);

    k_topk_cls1<<<8192, 256, 0, stream>>>(msq, w1t, cls_b1, hid);
    k_gemm_bt<0, 64><<<dim3(8, 128), 256, 0, stream>>>(hid, c2b, cls_b2, out, 8192, 1024, 1024, 1000, nullptr, nullptr);
  } else {
    // ---- fallback layout (128MB): 4-chunk G2 path ----
    __bf16* xb   = (__bf16*)(ws + 0);
    float*  msq  = (float*)(ws + 0);
    float*  y1   = (float*)(ws + 32 * MB);
    __bf16* outc = (__bf16*)(ws + 32 * MB);
    __bf16* mag1 = (__bf16*)(ws + 32 * MB);
    __bf16* hid  = (__bf16*)(ws + 48 * MB);
    __bf16* w1b  = (__bf16*)(ws + 64 * MB);
    __bf16* mag0 = (__bf16*)(ws + 64 * MB);
    __bf16* wfwb = (__bf16*)(ws + 96 * MB);
    __bf16* hb   = (__bf16*)(ws + 108 * MB);
    float*  w1t  = (float*)(ws + 108 * MB);
    __bf16* gwb  = (__bf16*)(ws + 124 * MB);
    __bf16* c2b  = (__bf16*)(ws + 126 * MB);

    k_cast_bf16<<<16384, 256, 0, stream>>>(x, xb);
    k_cast_weights<<<9216, 256, 0, stream>>>(proj_w, w1b, wf_w, wfwb, gate_w, gwb);
    k_cast_pad<<<1024, 256, 0, stream>>>(cls_w2, c2b, 1000, 1024);

    k_gemm_bt<0, 64><<<dim3(8, 128), 256, 0, stream>>>(xb, w1b, proj_b, y1, 8192, 1024, 2048, 1024, nullptr, nullptr);
    k_ln_gelu<<<8192, 256, 0, stream>>>(y1, ln_p_g, ln_p_b, hb);

    for (int c = 0; c < 4; ++c) {
      k_gemm_bt<1, 128><<<dim3(48, 16), 256, 0, stream>>>(hb + (size_t)c * 2048 * 1024, wfwb, wf_b,
                                                          outc, 2048, 6144, 1024, 6144, nullptr, nullptr);
      k_stage_c<<<2048, 256, 0, stream>>>(outc, ln_g, ln_b, phases, temperature,
                                          msq, mag0, c * 2048);
    }

    k_transpose1k<<<dim3(32, 32), 256, 0, stream>>>(cls_w1, w1t);
    k_gemm_bt<6, 64><<<dim3(8, 128), 256, 0, stream>>>(mag0, gwb, gate_b, nullptr, 8192, 1024, 1024, 1024, msq, mag1);
    k_gemm_bt<7, 64><<<dim3(8, 128), 256, 0, stream>>>(mag1, gwb, gate_b, nullptr, 8192, 1024, 1024, 1024, msq, nullptr);

    k_topk_cls1<<<8192, 256, 0, stream>>>(msq, w1t, cls_b1, hid);
    k_gemm_bt<0, 64><<<dim3(8, 128), 256, 0, stream>>>(hid, c2b, cls_b2, out, 8192, 1024, 1024, 1000, nullptr, nullptr);
  }
}

// Round 12
// 500.575 us; speedup vs baseline: 1.1251x; 1.0005x over previous
//
#include <hip/hip_runtime.h>
#include <cstdint>

typedef __attribute__((ext_vector_type(8))) __bf16 bf16x8;
typedef __attribute__((ext_vector_type(4))) __bf16 bf16x4;
typedef __attribute__((ext_vector_type(4))) float f32x4;
typedef unsigned long long u64;

__device__ __forceinline__ void gld_lds16(const void* g, void* l) {
  __builtin_amdgcn_global_load_lds(
      (const __attribute__((address_space(1))) void*)g,
      (__attribute__((address_space(3))) void*)l, 16, 0, 0);
}

__device__ __forceinline__ float block_sum(float v, float* scr) {
#pragma unroll
  for (int off = 32; off > 0; off >>= 1) v += __shfl_down(v, off, 64);
  const int w = threadIdx.x >> 6;
  __syncthreads();
  if ((threadIdx.x & 63) == 0) scr[w] = v;
  __syncthreads();
  float s = 0.f;
  const int nw = blockDim.x >> 6;
  for (int i = 0; i < nw; ++i) s += scr[i];
  return s;
}

// fast gelu: A&S 7.1.26 erf (|err|<1.5e-7) + hw exp
__device__ __forceinline__ float gelu_fast(float x) {
  const float ax = fabsf(x) * 0.70710678118654752f;
  const float t = 1.f / (1.f + 0.3275911f * ax);
  const float e = __expf(-ax * ax);
  float poly = 1.061405429f;
  poly = poly * t - 1.453152027f;
  poly = poly * t + 1.421413741f;
  poly = poly * t - 0.284496736f;
  poly = poly * t + 0.254829592f;
  const float erfax = 1.f - poly * t * e;
  const float er = copysignf(erfax, x);
  return 0.5f * x * (1.f + er);
}

// ---------------- casts ----------------
__global__ __launch_bounds__(256) void k_cast_bf16(const float* __restrict__ in,
                                                   __bf16* __restrict__ out) {
  const long i = ((long)blockIdx.x * 256 + threadIdx.x) * 4;
  f32x4 v = *(const f32x4*)(in + i);
  bf16x4 o = {(__bf16)v[0], (__bf16)v[1], (__bf16)v[2], (__bf16)v[3]};
  *(bf16x4*)(out + i) = o;
}

// combined weight casts: proj_w(2048 blk) | wf_w(6144 blk) | gate_w(1024 blk)
__global__ __launch_bounds__(256) void k_cast_weights(
    const float* __restrict__ pw, __bf16* __restrict__ w1b,
    const float* __restrict__ wfw, __bf16* __restrict__ wfwb,
    const float* __restrict__ gw, __bf16* __restrict__ gwb) {
  const int bid = blockIdx.x;
  const float* in;
  __bf16* out;
  long base;
  if (bid < 2048) { in = pw; out = w1b; base = (long)bid * 1024; }
  else if (bid < 8192) { in = wfw; out = wfwb; base = (long)(bid - 2048) * 1024; }
  else { in = gw; out = gwb; base = (long)(bid - 8192) * 1024; }
  const long i = base + threadIdx.x * 4;
  f32x4 v = *(const f32x4*)(in + i);
  bf16x4 o = {(__bf16)v[0], (__bf16)v[1], (__bf16)v[2], (__bf16)v[3]};
  *(bf16x4*)(out + i) = o;
}

__global__ __launch_bounds__(256) void k_cast_pad(const float* __restrict__ in,
                                                  __bf16* __restrict__ out,
                                                  int rows_real, int cols) {
  const long i = ((long)blockIdx.x * 256 + threadIdx.x) * 4;
  const int row = (int)(i / cols);
  const int col = (int)(i % cols);
  bf16x4 o;
  if (row < rows_real) {
    f32x4 v = *(const f32x4*)(in + (long)row * cols + col);
    o = (bf16x4){(__bf16)v[0], (__bf16)v[1], (__bf16)v[2], (__bf16)v[3]};
  } else {
    o = (bf16x4){(__bf16)0.f, (__bf16)0.f, (__bf16)0.f, (__bf16)0.f};
  }
  *(bf16x4*)(out + i) = o;
}

// ---------------- transpose 1024x1024 f32 ----------------
__global__ __launch_bounds__(256) void k_transpose1k(const float* __restrict__ in,
                                                     float* __restrict__ out) {
  __shared__ float t[32][33];
  const int tx = threadIdx.x & 31;
  const int ty = threadIdx.x >> 5;
  const int r0 = blockIdx.y * 32, c0 = blockIdx.x * 32;
#pragma unroll
  for (int k = 0; k < 4; ++k)
    t[ty + 8 * k][tx] = in[(long)(r0 + ty + 8 * k) * 1024 + c0 + tx];
  __syncthreads();
#pragma unroll
  for (int k = 0; k < 4; ++k)
    out[(long)(c0 + ty + 8 * k) * 1024 + r0 + tx] = t[tx][ty + 8 * k];
}

// ============ 256x256 8-wave BK=64 GEMM + LDS-bounce full-line epilogue ============
// A-resident XCD partition: each XCD owns gy/8 consecutive by (A-panels stay
// L2-resident), streams all bx (B-panels). Requires gy % 8 == 0.
__global__ __launch_bounds__(512, 1) void k_gemm256_bt(
    const __bf16* __restrict__ A, const __bf16* __restrict__ B,
    const float* __restrict__ bias, __bf16* __restrict__ C,
    int M, int N, int K) {
  __shared__ __align__(16) __bf16 lds[2][2][256 * 64];  // [slot][mat][row*64+k]
  const int tid = threadIdx.x;
  const int lane = tid & 63;
  const int wid = tid >> 6;
  const int wr = wid >> 2;
  const int wc = wid & 3;
  const int gx = gridDim.x, gy = gridDim.y;
  const int lin = blockIdx.y * gx + blockIdx.x;
  const int xcd = lin & 7;
  const int local = lin >> 3;        // [0, gx*gy/8)
  const int byq = gy >> 3;           // A-panels per XCD
  const int bx = local / byq;        // B streams
  const int by = xcd * byq + (local % byq);  // A resident
  const int m0 = by * 256, n0 = bx * 256;
  const int fr = lane & 15;
  const int fx = lane >> 4;
  const int px = lane & 7;

  const __bf16* Abase = A + (long)m0 * K;
  const __bf16* Bbase = B + (long)n0 * K;

  auto stage_q = [&](int slot, int kt, int mat, int half) {
    const __bf16* src = (mat ? Bbase : Abase) + kt * 64;
#pragma unroll
    for (int q = 0; q < 2; ++q) {
      const int idx = q * 512 + tid;
      const int r = idx >> 3;
      const int pblk = idx & 7;
      const int row = half * 128 + r;
      const int lblk = pblk ^ (r & 7);
      gld_lds16(src + (long)row * K + lblk * 8,
                (char*)&lds[slot][mat][row * 64 + pblk * 8]);
    }
  };
  auto frag = [&](int slot, int mat, int row, int ks) -> bf16x8 {
    return *(const bf16x8*)&lds[slot][mat][row * 64 + ((((ks << 2) + fx) ^ px) << 3)];
  };

  f32x4 acc[8][4] = {};
  const int nt = K >> 6;
#pragma unroll
  for (int qp = 0; qp < 4; ++qp) stage_q(0, 0, qp >> 1, qp & 1);

  const int arow = wr * 128 + fr;
  const int brow = wc * 64 + fr;

  for (int t = 0; t < nt; ++t) {
    const int sc = t & 1, sn = sc ^ 1;
    if (t + 1 < nt) {
#pragma unroll
      for (int qp = 0; qp < 4; ++qp) stage_q(sn, t + 1, qp >> 1, qp & 1);
      asm volatile("s_waitcnt vmcnt(8)" ::: "memory");
    } else {
      asm volatile("s_waitcnt vmcnt(0)" ::: "memory");
    }
    __builtin_amdgcn_sched_barrier(0);
    __builtin_amdgcn_s_barrier();
    bf16x8 b0[4], b1[4];
#pragma unroll
    for (int j = 0; j < 4; ++j) {
      b0[j] = frag(sc, 1, brow + j * 16, 0);
      b1[j] = frag(sc, 1, brow + j * 16, 1);
    }
    __builtin_amdgcn_s_setprio(1);
#pragma unroll
    for (int im = 0; im < 8; ++im) {
      bf16x8 x0 = frag(sc, 0, arow + im * 16, 0);
      bf16x8 x1 = frag(sc, 0, arow + im * 16, 1);
#pragma unroll
      for (int j = 0; j < 4; ++j) {
        acc[im][j] = __builtin_amdgcn_mfma_f32_16x16x32_bf16(x0, b0[j], acc[im][j], 0, 0, 0);
        acc[im][j] = __builtin_amdgcn_mfma_f32_16x16x32_bf16(x1, b1[j], acc[im][j], 0, 0, 0);
      }
    }
    __builtin_amdgcn_s_setprio(0);
    __builtin_amdgcn_s_barrier();
  }

  // ---- epilogue: bounce C tile through dead staging LDS ----
  __bf16* cb = (__bf16*)&lds[0][0][0];
  const int lm0 = wr * 128 + fx * 4;
  const int lc0 = wc * 64 + fr;
#pragma unroll
  for (int j = 0; j < 4; ++j) {
    const float bv = bias[n0 + lc0 + j * 16];
#pragma unroll
    for (int im = 0; im < 8; ++im)
#pragma unroll
      for (int r = 0; r < 4; ++r)
        cb[(lm0 + im * 16 + r) * 256 + lc0 + j * 16] = (__bf16)(acc[im][j][r] + bv);
  }
  __syncthreads();
#pragma unroll
  for (int q = 0; q < 16; ++q) {
    const int idx = q * 512 + tid;
    const int row = idx >> 5;
    const int c8 = (idx & 31) * 8;
    *(f32x4*)(C + (long)(m0 + row) * N + n0 + c8) = *(const f32x4*)(cb + row * 256 + c8);
  }
}

// ---------------- GEMM: C = A @ B^T + bias (128-col tiles) ----------------
// EPI: 0 f32 store (LDS-bounce full-line), 1 bf16 store (scatter; fallback),
//      6 gate1: msq *= f^2 streaming + mag bf16 out, 7 gate2: msq *= f^2 streaming
template <int EPI, int BM>
__global__ __launch_bounds__(256) void k_gemm_bt(
    const __bf16* __restrict__ A, const __bf16* __restrict__ B,
    const float* __restrict__ bias, void* __restrict__ Cout,
    int M, int N, int K, int Nreal,
    float* __restrict__ msq, __bf16* __restrict__ magOut) {
  constexpr int MR = BM / 32;
  constexpr int STAGE_B = (2 * BM * 32 + 2 * 128 * 32) * 2;
  constexpr int CB_B = BM * 64 * 4;
  constexpr int SMEM_B = STAGE_B > CB_B ? STAGE_B : CB_B;
  __shared__ __align__(16) char smem[SMEM_B];
  __bf16* As = (__bf16*)smem;
  __bf16* Bs = (__bf16*)(smem + (size_t)2 * BM * 32 * 2);
  float* cb = (float*)smem;  // bounce region (BM x 64 f32)
  const int tid = threadIdx.x;
  const int lane = tid & 63;
  const int wid = tid >> 6;
  const int wr = wid >> 1, wc = wid & 1;

  const int gx = gridDim.x, gy = gridDim.y;
  const int nwg = gx * gy;
  int bx, by;
  if ((nwg & 7) == 0) {
    const int lin = blockIdx.y * gx + blockIdx.x;
    const int cpx = nwg >> 3;
    const int w = (lin & 7) * cpx + (lin >> 3);
    bx = w / gy;
    by = w % gy;
  } else {
    bx = blockIdx.x;
    by = blockIdx.y;
  }
  const int m0 = by * BM;
  const int n0 = bx * 128;
  const int frow = lane & 15;
  const int fk = (lane >> 4) * 8;
  f32x4 acc[MR][4] = {};

  auto stage = [&](int buf, int k0) {
    const __bf16* Ab = A + (long)m0 * K + k0;
    const __bf16* Bb = B + (long)n0 * K + k0;
    __bf16* Asb = As + buf * BM * 32;
    __bf16* Bsb = Bs + buf * 128 * 32;
#pragma unroll
    for (int q = 0; q < BM / 64; ++q) {
      const int idx = q * 256 + tid;
      const int row = idx >> 2;
      const int col = (idx & 3) * 8;
      gld_lds16(Ab + (long)row * K + col, (char*)Asb + idx * 16);
    }
#pragma unroll
    for (int q = 0; q < 2; ++q) {
      const int idx = q * 256 + tid;
      const int row = idx >> 2;
      const int col = (idx & 3) * 8;
      gld_lds16(Bb + (long)row * K + col, (char*)Bsb + idx * 16);
    }
  };

  const int nt = K >> 5;
  int cur = 0;
  stage(0, 0);
  __syncthreads();
  for (int t = 0; t < nt; ++t) {
    if (t + 1 < nt) stage(cur ^ 1, (t + 1) << 5);
    bf16x8 af[MR], bfr[4];
#pragma unroll
    for (int i = 0; i < MR; ++i)
      af[i] = *(const bf16x8*)(As + cur * BM * 32 + (wr * (BM / 2) + i * 16 + frow) * 32 + fk);
#pragma unroll
    for (int i = 0; i < 4; ++i)
      bfr[i] = *(const bf16x8*)(Bs + cur * 128 * 32 + (wc * 64 + i * 16 + frow) * 32 + fk);
#pragma unroll
    for (int im = 0; im < MR; ++im)
#pragma unroll
      for (int in = 0; in < 4; ++in)
        acc[im][in] = __builtin_amdgcn_mfma_f32_16x16x32_bf16(af[im], bfr[in],
                                                              acc[im][in], 0, 0, 0);
    __syncthreads();
    cur ^= 1;
  }

  if (EPI == 0 || EPI == 6 || EPI == 7) {
    // bounce via LDS in two 64-col halves -> full-line streaming epilogue
#pragma unroll 1
    for (int h = 0; h < 2; ++h) {
      __syncthreads();
      if (wc == h) {
#pragma unroll
        for (int in = 0; in < 4; ++in) {
          const int col = n0 + h * 64 + in * 16 + frow;
          const float bv = (col < Nreal) ? bias[col] : 0.f;
          const int lcc = in * 16 + frow;
#pragma unroll
          for (int im = 0; im < MR; ++im)
#pragma unroll
            for (int r = 0; r < 4; ++r) {
              const float v = acc[im][in][r] + bv;
              float sv;
              if (EPI == 0) {
                sv = v;
              } else {
                const float f = 1.f / (1.f + __expf(-v)) + 0.1f;
                sv = f * f;
              }
              cb[(wr * (BM / 2) + (lane >> 4) * 4 + im * 16 + r) * 64 + lcc] = sv;
            }
        }
      }
      __syncthreads();
#pragma unroll
      for (int q = 0; q < BM / 16; ++q) {
        const int idx = q * 256 + tid;
        const int row = idx >> 4;
        const int c4 = (idx & 15) * 4;
        const int gc = n0 + h * 64 + c4;
        if (EPI == 0) {
          if (gc < Nreal)
            *(f32x4*)((float*)Cout + (long)(m0 + row) * Nreal + gc) =
                *(const f32x4*)(cb + row * 64 + c4);
        } else {
          const long gix = (long)(m0 + row) * Nreal + gc;
          f32x4 m = *(const f32x4*)(msq + gix);
          const f32x4 f2 = *(const f32x4*)(cb + row * 64 + c4);
          m[0] *= f2[0]; m[1] *= f2[1]; m[2] *= f2[2]; m[3] *= f2[3];
          *(f32x4*)(msq + gix) = m;
          if (EPI == 6) {
            bf16x4 mg = {(__bf16)sqrtf(m[0] + 1e-8f), (__bf16)sqrtf(m[1] + 1e-8f),
                         (__bf16)sqrtf(m[2] + 1e-8f), (__bf16)sqrtf(m[3] + 1e-8f)};
            *(bf16x4*)(magOut + gix) = mg;
          }
        }
      }
    }
  } else {
    const int crow0 = m0 + wr * (BM / 2) + (lane >> 4) * 4;
    const int ccol0 = n0 + wc * 64 + (lane & 15);
#pragma unroll
    for (int in = 0; in < 4; ++in) {
      const int col = ccol0 + in * 16;
      if (col >= Nreal) continue;
      const float bv = bias[col];
#pragma unroll
      for (int im = 0; im < MR; ++im) {
#pragma unroll
        for (int r = 0; r < 4; ++r) {
          const long row = crow0 + im * 16 + r;
          ((__bf16*)Cout)[row * Nreal + col] = (__bf16)(acc[im][in][r] + bv);
        }
      }
    }
  }
}

// ---------------- LN (over 1024) + gelu -> bf16 ----------------
__global__ __launch_bounds__(256) void k_ln_gelu(const float* __restrict__ y,
                                                 const float* __restrict__ g,
                                                 const float* __restrict__ b,
                                                 __bf16* __restrict__ h) {
  __shared__ float scr[8];
  const int tid = threadIdx.x;
  const long row = blockIdx.x;
  const float* yr = y + row * 1024;
  f32x4 v = *(const f32x4*)(yr + tid * 4);
  float ls = v[0] + v[1] + v[2] + v[3];
  const float mu = block_sum(ls, scr) * (1.f / 1024.f);
  float lss = 0.f;
#pragma unroll
  for (int j = 0; j < 4; ++j) {
    const float d = v[j] - mu;
    lss += d * d;
  }
  const float var = block_sum(lss, scr) * (1.f / 1024.f);
  const float rstd = rsqrtf(var + 1e-5f);
  bf16x4 o;
#pragma unroll
  for (int j = 0; j < 4; ++j) {
    const int c = tid * 4 + j;
    const float t = (v[j] - mu) * rstd * g[c] + b[c];
    o[j] = (__bf16)gelu_fast(t);
  }
  *(bf16x4*)(h + row * 1024 + tid * 4) = o;
}

// ---------------- stage C: outputs msq (f32) + mag0 (bf16) ----------------
__global__ __launch_bounds__(256) void k_stage_c(
    const __bf16* __restrict__ outb, const float* __restrict__ ln_g,
    const float* __restrict__ ln_b, const float* __restrict__ phases,
    const float* __restrict__ temp, float* __restrict__ msq,
    __bf16* __restrict__ mag0, int b0) {
  __shared__ float wrs[3][1024];
  __shared__ float wis[3][1024];
  __shared__ float gbuf[2048];
  __shared__ float scr[8];
  const int tid = threadIdx.x;
  const long b = blockIdx.x;

#pragma unroll 1
  for (int s = 0; s < 3; ++s) {
    const __bf16* src = outb + b * 6144 + s * 2048;
    bf16x8 v8 = *(const bf16x8*)(src + tid * 8);
    float x[8];
#pragma unroll
    for (int j = 0; j < 8; ++j) x[j] = (float)v8[j];
    float ls = 0.f;
#pragma unroll
    for (int j = 0; j < 8; ++j) ls += x[j];
    const float mu = block_sum(ls, scr) * (1.f / 2048.f);
    float lss = 0.f;
#pragma unroll
    for (int j = 0; j < 8; ++j) {
      const float d = x[j] - mu;
      lss += d * d;
    }
    const float var = block_sum(lss, scr) * (1.f / 2048.f);
    const float rstd = rsqrtf(var + 1e-5f);
    const float* lg = ln_g + s * 2048;
    const float* lb = ln_b + s * 2048;
    float nsq = 0.f;
#pragma unroll
    for (int j = 0; j < 8; ++j) {
      const int e = tid * 8 + j;
      const float yv = (x[j] - mu) * rstd * lg[e] + lb[e];
      const float gv = __expf(-yv * yv);
      gbuf[e] = gv;
      nsq += gv * gv;
    }
    const float normsq = block_sum(nsq, scr) + 1e-8f;
    const float factor = sqrtf(2.25f / normsq);
    const float ph = phases[s];
    const float cs = cosf(ph), sn = sinf(ph);
#pragma unroll
    for (int j = 0; j < 4; ++j) {
      const int h = j * 256 + tid;
      const float a = gbuf[h] * factor;
      const float bb = gbuf[h + 1024] * factor;
      wrs[s][h] = a * cs - bb * sn;
      wis[s][h] = a * sn + bb * cs;
    }
    __syncthreads();
  }

  float mr[4];
  float pmn = 0.f;
#pragma unroll
  for (int j = 0; j < 4; ++j) {
    const int h = j * 256 + tid;
    const float m = (wrs[0][h] + wrs[1][h] + wrs[2][h]) * (1.f / 3.f);
    mr[j] = m;
    pmn += m * m;
  }
  const float mnorm = sqrtf(block_sum(pmn, scr)) + 1e-8f;
  float csim[3];
#pragma unroll 1
  for (int s = 0; s < 3; ++s) {
    float pd = 0.f, pw = 0.f;
#pragma unroll
    for (int j = 0; j < 4; ++j) {
      const int h = j * 256 + tid;
      const float w = wrs[s][h];
      pd += w * mr[j];
      pw += w * w;
    }
    const float dot = block_sum(pd, scr);
    const float wn = sqrtf(block_sum(pw, scr)) + 1e-8f;
    csim[s] = dot / (wn * mnorm);
  }
  const float T = temp[0];
  const float t0 = csim[0] / T, t1 = csim[1] / T, t2 = csim[2] / T;
  const float mx = fmaxf(t0, fmaxf(t1, t2));
  const float e0 = __expf(t0 - mx), e1 = __expf(t1 - mx), e2 = __expf(t2 - mx);
  const float inv = 1.f / (e0 + e1 + e2);
  const float w0 = e0 * inv, w1 = e1 * inv, w2 = e2 * inv;
#pragma unroll
  for (int j = 0; j < 4; ++j) {
    const int h = j * 256 + tid;
    const float sr = wrs[0][h] * w0 + wrs[1][h] * w1 + wrs[2][h] * w2;
    const float si = wis[0][h] * w0 + wis[1][h] * w1 + wis[2][h] * w2;
    const float m2 = sr * sr + si * si;
    msq[(long)(b0 + b) * 1024 + h] = m2;
    mag0[(long)(b0 + b) * 1024 + h] = (__bf16)sqrtf(m2 + 1e-8f);
  }
}

// ---------------- fused top-8 (u64-key over msq) + sparse cls1 ----------------
__global__ __launch_bounds__(256) void k_topk_cls1(
    const float* __restrict__ msq,
    const float* __restrict__ w1t, const float* __restrict__ b1,
    __bf16* __restrict__ hid) {
  __shared__ u64 candk[32];
  __shared__ u64 selk_s[8];
  __shared__ float ssum_s;
  const int tid = threadIdx.x;
  const int lane = tid & 63;
  const int wv = tid >> 6;
  const long b = blockIdx.x;

  f32x4 mv = *(const f32x4*)(msq + b * 1024 + tid * 4);
  u64 key[4];
#pragma unroll
  for (int j = 0; j < 4; ++j)
    key[j] = ((u64)__float_as_uint(mv[j]) << 32) | (unsigned)(~(unsigned)(tid * 4 + j));
  u64 lm = key[0];
  int jm = 0;
#pragma unroll
  for (int j = 1; j < 4; ++j)
    if (key[j] > lm) { lm = key[j]; jm = j; }

#pragma unroll 1
  for (int it = 0; it < 8; ++it) {
    u64 bk = lm;
#pragma unroll
    for (int m = 1; m < 64; m <<= 1) {
      const u64 ok = __shfl_xor(bk, m, 64);
      bk = ok > bk ? ok : bk;
    }
    if (lane == 0) candk[wv * 8 + it] = bk;
    if (bk == lm) {
      key[jm] = 0ULL;
      lm = key[0]; jm = 0;
#pragma unroll
      for (int j = 1; j < 4; ++j)
        if (key[j] > lm) { lm = key[j]; jm = j; }
    }
  }
  __syncthreads();

  if (wv == 0) {
    u64 ck = (lane < 32) ? candk[lane] : 0ULL;
    float ss = 0.f;
#pragma unroll 1
    for (int it = 0; it < 8; ++it) {
      u64 bk = ck;
#pragma unroll
      for (int m = 1; m < 64; m <<= 1) {
        const u64 ok = __shfl_xor(bk, m, 64);
        bk = ok > bk ? ok : bk;
      }
      if (ck == bk) ck = 0ULL;
      if (lane == 0) {
        selk_s[it] = bk;
        ss += __uint_as_float((unsigned)(bk >> 32));
      }
    }
    if (lane == 0) ssum_s = ss;
  }
  __syncthreads();

  const float denom = 1.f / (ssum_s + 1e-8f);
  float p[8];
  int idx[8];
#pragma unroll
  for (int k = 0; k < 8; ++k) {
    const u64 kk = selk_s[k];
    p[k] = __uint_as_float((unsigned)(kk >> 32)) * denom;
    idx[k] = (int)(~(unsigned)kk & 1023u);
  }

  const int o0 = tid * 4;
  float acc0 = b1[o0], acc1 = b1[o0 + 1], acc2 = b1[o0 + 2], acc3 = b1[o0 + 3];
#pragma unroll
  for (int k = 0; k < 8; ++k) {
    const f32x4 wrow = *(const f32x4*)(w1t + (long)idx[k] * 1024 + o0);
    acc0 += p[k] * wrow[0];
    acc1 += p[k] * wrow[1];
    acc2 += p[k] * wrow[2];
    acc3 += p[k] * wrow[3];
  }
  bf16x4 o = {(__bf16)gelu_fast(acc0), (__bf16)gelu_fast(acc1),
              (__bf16)gelu_fast(acc2), (__bf16)gelu_fast(acc3)};
  *(bf16x4*)(hid + b * 1024 + o0) = o;
}

extern "C" void kernel_launch(void* const* d_in, const int* in_sizes, int n_in,
                              void* d_out, int out_size, void* d_ws, size_t ws_size,
                              hipStream_t stream) {
  const float* x      = (const float*)d_in[0];
  const float* proj_w = (const float*)d_in[1];
  const float* proj_b = (const float*)d_in[2];
  const float* ln_p_g = (const float*)d_in[3];
  const float* ln_p_b = (const float*)d_in[4];
  const float* wf_w   = (const float*)d_in[5];
  const float* wf_b   = (const float*)d_in[6];
  const float* ln_g   = (const float*)d_in[7];
  const float* ln_b   = (const float*)d_in[8];
  const float* temperature = (const float*)d_in[9];
  const float* phases = (const float*)d_in[10];
  const float* gate_w = (const float*)d_in[11];
  const float* gate_b = (const float*)d_in[12];
  const float* cls_w1 = (const float*)d_in[13];
  const float* cls_b1 = (const float*)d_in[14];
  const float* cls_w2 = (const float*)d_in[15];
  const float* cls_b2 = (const float*)d_in[16];
  float* out = (float*)d_out;
  (void)in_sizes; (void)n_in; (void)out_size;

  char* ws = (char*)d_ws;
  const size_t MB = 1024 * 1024;

  if (ws_size >= 196 * MB) {
    // ---- full layout (196MB) ----
    __bf16* xb   = (__bf16*)(ws + 0);
    float*  msq  = (float*)(ws + 0);
    float*  y1   = (float*)(ws + 32 * MB);
    __bf16* mag0 = (__bf16*)(ws + 32 * MB);
    __bf16* mag1 = (__bf16*)(ws + 48 * MB);
    __bf16* outb = (__bf16*)(ws + 64 * MB);
    __bf16* hid  = (__bf16*)(ws + 64 * MB);
    float*  w1t  = (float*)(ws + 96 * MB);
    __bf16* hb   = (__bf16*)(ws + 160 * MB);
    __bf16* wfwb = (__bf16*)(ws + 176 * MB);
    __bf16* gwb  = (__bf16*)(ws + 188 * MB);
    __bf16* c2b  = (__bf16*)(ws + 190 * MB);
    __bf16* w1b  = (__bf16*)(ws + 192 * MB);

    k_cast_bf16<<<16384, 256, 0, stream>>>(x, xb);
    k_cast_weights<<<9216, 256, 0, stream>>>(proj_w, w1b, wf_w, wfwb, gate_w, gwb);
    k_cast_pad<<<1024, 256, 0, stream>>>(cls_w2, c2b, 1000, 1024);

    k_gemm_bt<0, 64><<<dim3(8, 128), 256, 0, stream>>>(xb, w1b, proj_b, y1, 8192, 1024, 2048, 1024, nullptr, nullptr);
    k_ln_gelu<<<8192, 256, 0, stream>>>(y1, ln_p_g, ln_p_b, hb);

    k_gemm256_bt<<<dim3(24, 32), 512, 0, stream>>>(hb, wfwb, wf_b, outb, 8192, 6144, 1024);
    k_stage_c<<<8192, 256, 0, stream>>>(outb, ln_g, ln_b, phases, temperature, msq, mag0, 0);

    k_transpose1k<<<dim3(32, 32), 256, 0, stream>>>(cls_w1, w1t);
    k_gemm_bt<6, 64><<<dim3(8, 128), 256, 0, stream>>>(mag0, gwb, gate_b, nullptr, 8192, 1024, 1024, 1024, msq, mag1);
    k_gemm_bt<7, 64><<<dim3(8, 128), 256, 0, stream>>>(mag1, gwb, gate_b, nullptr, 8192, 1024, 1024, 1024, msq, nullptr);

    k_topk_cls1<<<8192, 256, 0, stream>>>(msq, w1t, cls_b1, hid);
    k_gemm_bt<0, 64><<<dim3(8, 128), 256, 0, stream>>>(hid, c2b, cls_b2, out, 8192, 1024, 1024, 1000, nullptr, nullptr);
  } else {
    // ---- fallback layout (128MB): 4-chunk G2 path ----
    __bf16* xb   = (__bf16*)(ws + 0);
    float*  msq  = (float*)(ws + 0);
    float*  y1   = (float*)(ws + 32 * MB);
    __bf16* outc = (__bf16*)(ws + 32 * MB);
    __bf16* mag1 = (__bf16*)(ws + 32 * MB);
    __bf16* hid  = (__bf16*)(ws + 48 * MB);
    __bf16* w1b  = (__bf16*)(ws + 64 * MB);
    __bf16* mag0 = (__bf16*)(ws + 64 * MB);
    __bf16* wfwb = (__bf16*)(ws + 96 * MB);
    __bf16* hb   = (__bf16*)(ws + 108 * MB);
    float*  w1t  = (float*)(ws + 108 * MB);
    __bf16* gwb  = (__bf16*)(ws + 124 * MB);
    __bf16* c2b  = (__bf16*)(ws + 126 * MB);

    k_cast_bf16<<<16384, 256, 0, stream>>>(x, xb);
    k_cast_weights<<<9216, 256, 0, stream>>>(proj_w, w1b, wf_w, wfwb, gate_w, gwb);
    k_cast_pad<<<1024, 256, 0, stream>>>(cls_w2, c2b, 1000, 1024);

    k_gemm_bt<0, 64><<<dim3(8, 128), 256, 0, stream>>>(xb, w1b, proj_b, y1, 8192, 1024, 2048, 1024, nullptr, nullptr);
    k_ln_gelu<<<8192, 256, 0, stream>>>(y1, ln_p_g, ln_p_b, hb);

    for (int c = 0; c < 4; ++c) {
      k_gemm_bt<1, 128><<<dim3(48, 16), 256, 0, stream>>>(hb + (size_t)c * 2048 * 1024, wfwb, wf_b,
                                                          outc, 2048, 6144, 1024, 6144, nullptr, nullptr);
      k_stage_c<<<2048, 256, 0, stream>>>(outc, ln_g, ln_b, phases, temperature,
                                          msq, mag0, c * 2048);
    }

    k_transpose1k<<<dim3(32, 32), 256, 0, stream>>>(cls_w1, w1t);
    k_gemm_bt<6, 64><<<dim3(8, 128), 256, 0, stream>>>(mag0, gwb, gate_b, nullptr, 8192, 1024, 1024, 1024, msq, mag1);
    k_gemm_bt<7, 64><<<dim3(8, 128), 256, 0, stream>>>(mag1, gwb, gate_b, nullptr, 8192, 1024, 1024, 1024, msq, nullptr);

    k_topk_cls1<<<8192, 256, 0, stream>>>(msq, w1t, cls_b1, hid);
    k_gemm_bt<0, 64><<<dim3(8, 128), 256, 0, stream>>>(hid, c2b, cls_b2, out, 8192, 1024, 1024, 1000, nullptr, nullptr);
  }
}